// Round 16
// baseline (147.325 us; speedup 1.0000x reference)
//
#include <hip/hip_runtime.h>
#include <stdint.h>

typedef _Float16 f16;
typedef _Float16 f16x4 __attribute__((ext_vector_type(4)));
typedef _Float16 f16x8 __attribute__((ext_vector_type(8)));
typedef __fp16 hf16x2 __attribute__((ext_vector_type(2)));   // cvt_pkrtz return type
typedef float f32x4 __attribute__((ext_vector_type(4)));
typedef float f32x16 __attribute__((ext_vector_type(16)));
typedef unsigned u32;
typedef unsigned uint2v __attribute__((ext_vector_type(2)));

static constexpr int Bb = 2, Ss = 2048, Dd = 1024, Hh = 16, HDd = 64;
static constexpr int M_ROWS = Bb * Ss; // 4096

// ---- workspace layout (bytes) ----
static constexpr size_t OFF_X   = 0;                       // Xq,Xk,Xv f16: 3 * 8 MiB
static constexpr size_t OFF_WT  = 24ull << 20;             // WtQ..WtO f16: 4 * 2 MiB
static constexpr size_t OFF_QKV = 32ull << 20;             // Q,K row-major; V transposed [b][h][d][s]
static constexpr size_t OFF_ATT = 56ull << 20;             // attn f16: 8 MiB
static constexpr size_t OFF_MB  = 64ull << 20;             // mask bits: 1 MiB

__device__ __forceinline__ void gll16(const void* g, void* l) {
  __builtin_amdgcn_global_load_lds((__attribute__((address_space(1))) const void*)g,
                                   (__attribute__((address_space(3))) void*)l, 16, 0, 0);
}

// [rows][64 f16] tile (row = 128 B): byte addr of 16B slot `slot`, XOR-swizzled.
__device__ __forceinline__ int lds_byte(int row, int slot) {
  return row * 128 + (((slot ^ (row & 7)) & 7) << 4);
}

// [rows][32 f16] tile (row = 64 B): byte addr of 16B slot `slot`, XOR-swizzled.
__device__ __forceinline__ int lds_byte32(int row, int slot) {
  return row * 64 + (((slot ^ (row & 3)) & 3) << 4);
}

// raw v_exp_f32 (input already in log2 domain)
__device__ __forceinline__ float ex2(float x) {
  float r; asm("v_exp_f32 %0, %1" : "=v"(r) : "v"(x)); return r;
}

union H2U { hf16x2 h; u32 u; };

// ---------------- prep: mask bits + weights^T->f16 + X->f16 ----------------
__global__ __launch_bounds__(256) void prep(const int* __restrict__ mask,
                                            unsigned* __restrict__ bits,
                                            const float* __restrict__ qin,
                                            const float* __restrict__ kin,
                                            const float* __restrict__ vin,
                                            const float* __restrict__ wq,
                                            const float* __restrict__ wk,
                                            const float* __restrict__ wv,
                                            const float* __restrict__ wo,
                                            f16* __restrict__ wt,
                                            f16* __restrict__ X) {
  const int bid = blockIdx.x;
  __shared__ float t[32][33];
  if (bid < 32768) {
    size_t i = (size_t)bid * 256 + threadIdx.x;    // one thread per mask int
    int v = mask[i];
    unsigned long long bm = __ballot(v != 0);
    if ((threadIdx.x & 63) == 0) {
      size_t w = i >> 5;
      bits[w]     = (unsigned)bm;
      bits[w + 1] = (unsigned)(bm >> 32);
    }
  } else if (bid < 36864) {
    const int wb = bid - 32768;                    // z*1024 + by*32 + bx
    const int z = wb >> 10, by = (wb >> 5) & 31, bx = wb & 31;
    const float* W = z == 0 ? wq : z == 1 ? wk : z == 2 ? wv : wo;
    f16* Wt = wt + (size_t)z * Dd * Dd;
    const int tx = threadIdx.x & 31, ty = threadIdx.x >> 5;   // (32, 8)
    const int k0 = by * 32, n0 = bx * 32;
    for (int i = 0; i < 32; i += 8) t[ty + i][tx] = W[(size_t)(k0 + ty + i) * Dd + n0 + tx];
    __syncthreads();
    for (int i = 0; i < 32; i += 8) Wt[(size_t)(n0 + ty + i) * Dd + k0 + tx] = (f16)t[tx][ty + i];
  } else {
    const int xb = bid - 36864;                    // 0..12287 (4096 blocks per z)
    const int zz = xb >> 12;
    const float* src = zz == 0 ? qin : zz == 1 ? kin : vin;
    f16* dst = X + (size_t)zz * M_ROWS * Dd;
    size_t li = (size_t)(xb & 4095) * 256 + threadIdx.x;   // float4 index
    float4 a = reinterpret_cast<const float4*>(src)[li];
    f16x4 o;
    o[0] = (f16)a.x; o[1] = (f16)a.y; o[2] = (f16)a.z; o[3] = (f16)a.w;
    *reinterpret_cast<f16x4*>(dst + li * 4) = o;
  }
}

// ---------------- QKV GEMM: BK=32, all-gll16 f16, 32KB LDS -> 3 blocks/CU, all resident ----------------
// z==0: output scaled by 0.125*log2e; z==2: output stored TRANSPOSED as Vt[b][h][d][s]
__global__ __launch_bounds__(256) void gemm_qkv(const f16* __restrict__ Xbase,
                                                const f16* __restrict__ Btbase,
                                                const float* __restrict__ b0,
                                                const float* __restrict__ b1,
                                                const float* __restrict__ b2,
                                                f16* __restrict__ Cbase) {
  constexpr int K = Dd, N = Dd;
  const int f = blockIdx.x;                 // 0..767
  const int z = f >> 8, i = f & 255;
  const int xg = i & 7, sl = i >> 3;        // XCD-chunked m-panel map (R10)
  const int m0 = (xg * 4 + (sl >> 3)) * 128, n0 = (sl & 7) * 128;
  const f16* A  = Xbase  + (size_t)z * M_ROWS * K;
  const f16* Bt = Btbase + (size_t)z * N * K;
  const float* bias = z == 0 ? b0 : z == 1 ? b1 : b2;

  __shared__ char smem[32768];              // buf[2] x (As 8K | Bs 8K)
  const int tid = threadIdx.x, l = tid & 63, w = tid >> 6;   // w 0..3
  const int li = l & 15, gq = l >> 4;
  const int wm = (w >> 1) * 64, wn = (w & 1) * 64;
  const int sr = l >> 2, ss = l & 3;        // BK=32 staging: row-in-chunk 0..15, slot 0..3
  const int scol = ((ss ^ (sr & 3)) << 3);  // pre-swizzled source col (f16 elems)

  f32x4 acc[4][4];
  for (int mi = 0; mi < 4; mi++)
    for (int ni = 0; ni < 4; ni++) acc[mi][ni] = f32x4{0.f, 0.f, 0.f, 0.f};

  // prologue: stage tile 0 into buf0 (A: 8 chunks of 16 rows, B same; 2 each per wave)
#pragma unroll
  for (int c = 0; c < 2; c++) {
    int chunk = w * 2 + c, r = chunk * 16 + sr;
    gll16(A  + (size_t)(m0 + r) * K + scol, smem + chunk * 1024);
    gll16(Bt + (size_t)(n0 + r) * K + scol, smem + 8192 + chunk * 1024);
  }

  for (int it = 0; it < 32; it++) {
    __syncthreads();                        // stage(it) drained; buf[it^1] reads done
    char* Asc = smem + (it & 1) * 16384;
    char* Bsc = Asc + 8192;
    if (it < 31) {                          // issue stage(it+1): flies under compute(it)
      char* Asn = smem + ((it + 1) & 1) * 16384;
      const int kn = (it + 1) * 32;
#pragma unroll
      for (int c = 0; c < 2; c++) {
        int chunk = w * 2 + c, r = chunk * 16 + sr;
        gll16(A  + (size_t)(m0 + r) * K + kn + scol, Asn + chunk * 1024);
        gll16(Bt + (size_t)(n0 + r) * K + kn + scol, Asn + 8192 + chunk * 1024);
      }
    }
    f16x8 af[4], bf[4];
#pragma unroll
    for (int ii = 0; ii < 4; ii++) {
      af[ii] = *(const f16x8*)(Asc + lds_byte32(wm + ii * 16 + li, gq));
      bf[ii] = *(const f16x8*)(Bsc + lds_byte32(wn + ii * 16 + li, gq));
    }
#pragma unroll
    for (int mi = 0; mi < 4; mi++)
#pragma unroll
      for (int ni = 0; ni < 4; ni++)
        acc[mi][ni] = __builtin_amdgcn_mfma_f32_16x16x32_f16(af[mi], bf[ni], acc[mi][ni], 0, 0, 0);
  }

  const float scl = (z == 0) ? 0.18033688011112042f : 1.0f;   // 0.125*log2e
  if (z == 2) {
    // transposed V: Vt[(b*16+h)*64 + d][s], packed f16x4 along s
    f16* Vt = Cbase + (size_t)2 * M_ROWS * N;
#pragma unroll
    for (int mi = 0; mi < 4; mi++)
#pragma unroll
      for (int ni = 0; ni < 4; ni++) {
        const int col = n0 + wn + ni * 16 + li;        // h*64 + d
        const int r0  = m0 + wm + mi * 16 + gq * 4;    // global s index (4-aligned)
        const int bb_ = r0 >> 11, s = r0 & 2047;
        const float bv = bias[col];
        f16x4 pk;
#pragma unroll
        for (int j = 0; j < 4; j++) pk[j] = (f16)(acc[mi][ni][j] + bv);
        *(f16x4*)(Vt + ((size_t)(bb_ * Hh) << 17) + (size_t)col * Ss + s) = pk;
      }
  } else {
    for (int mi = 0; mi < 4; mi++)
      for (int ni = 0; ni < 4; ni++) {
        const int r0  = m0 + wm + mi * 16 + gq * 4;
        const int col = n0 + wn + ni * 16 + li;
        const float bb = bias[col];
#pragma unroll
        for (int j = 0; j < 4; j++) {
          float val = (acc[mi][ni][j] + bb) * scl;
          Cbase[(size_t)z * M_ROWS * N + (size_t)(r0 + j) * N + col] = (f16)val;
        }
      }
  }
}

// ---------------- output GEMM: 2-phase double-buffered, f16 A (attn), fp32 out ----------------
__global__ __launch_bounds__(256) void gemm_out(const f16* __restrict__ A,
                                                const f16* __restrict__ Bt,
                                                const float* __restrict__ bias,
                                                float* __restrict__ C) {
  constexpr int K = Dd, N = Dd;
  const int f = blockIdx.x;                 // 0..255
  const int xg = f & 7, sl = f >> 3;
  const int m0 = (xg * 4 + (sl >> 3)) * 128, n0 = (sl & 7) * 128;
  __shared__ char smem[65536];              // buf[2] x (As 16K | Bs 16K)
  const int tid = threadIdx.x, l = tid & 63, w = tid >> 6;
  const int li = l & 15, gq = l >> 4;
  const int wm = (w >> 1) * 64, wn = (w & 1) * 64;
  const int sr = l >> 3, ss = l & 7;
  const int scol = ((ss ^ sr) << 3);

  f32x4 acc[4][4];
  for (int mi = 0; mi < 4; mi++)
    for (int ni = 0; ni < 4; ni++) acc[mi][ni] = f32x4{0.f, 0.f, 0.f, 0.f};

  // prologue: stage tile 0 into buf0
#pragma unroll
  for (int c = 0; c < 4; c++) {
    int chunk = w * 4 + c, r = chunk * 8 + sr;
    gll16(A  + (size_t)(m0 + r) * K + scol, smem + chunk * 1024);
    gll16(Bt + (size_t)(n0 + r) * K + scol, smem + 16384 + chunk * 1024);
  }

  int cur = 0;
  for (int it = 0; it < 16; it++) {
    __syncthreads();
    char* Asc = smem + cur * 32768;
    char* Bsc = Asc + 16384;
    if (it < 15) {
      char* Asn = smem + (cur ^ 1) * 32768;
      const int kn = (it + 1) * 64;
#pragma unroll
      for (int c = 0; c < 4; c++) {
        int chunk = w * 4 + c, r = chunk * 8 + sr;
        gll16(A  + (size_t)(m0 + r) * K + kn + scol, Asn + chunk * 1024);
        gll16(Bt + (size_t)(n0 + r) * K + kn + scol, Asn + 16384 + chunk * 1024);
      }
    }
#pragma unroll
    for (int ks = 0; ks < 2; ks++) {
      f16x8 af[4], bf[4];
#pragma unroll
      for (int ii = 0; ii < 4; ii++) {
        af[ii] = *(const f16x8*)(Asc + lds_byte(wm + ii * 16 + li, ks * 4 + gq));
        bf[ii] = *(const f16x8*)(Bsc + lds_byte(wn + ii * 16 + li, ks * 4 + gq));
      }
#pragma unroll
      for (int mi = 0; mi < 4; mi++)
#pragma unroll
        for (int ni = 0; ni < 4; ni++)
          acc[mi][ni] = __builtin_amdgcn_mfma_f32_16x16x32_f16(af[mi], bf[ni], acc[mi][ni], 0, 0, 0);
    }
    cur ^= 1;
  }

  for (int mi = 0; mi < 4; mi++)
    for (int ni = 0; ni < 4; ni++) {
      const int r0  = m0 + wm + mi * 16 + gq * 4;
      const int col = n0 + wn + ni * 16 + li;
      const float bb = bias[col];
#pragma unroll
      for (int j = 0; j < 4; j++)
        C[(size_t)(r0 + j) * N + col] = acc[mi][ni][j] + bb;
    }
}

// ---------------- fused attention (split-k, 8 waves, defer-max exp2 softmax) — proven ----------------
__global__ __launch_bounds__(512, 4) void attn_fused(const f16* __restrict__ Qp,
                                                     const f16* __restrict__ Kp,
                                                     const f16* __restrict__ Vt,
                                                     const u32* __restrict__ mbits,
                                                     f16* __restrict__ outp) {
  // XCD-aware decode: all 16 q-tiles of one (b,h) land on one XCD for K/V L2 reuse
  const int flat = blockIdx.x;                 // 0..511
  const int xcd = flat & 7, jj = flat >> 3;    // jj 0..63
  const int qt = jj & 15;
  const int hb = xcd * 4 + (jj >> 4);          // 0..31
  const int h = hb & 15, b = hb >> 4;

  const int tid = threadIdx.x, l = tid & 63, w = tid >> 6;   // w 0..7
  const int lo = l & 31, hi = l >> 5;
  const int half = w >> 2, wsub = w & 3;
  const int q0 = qt * 128, wq = wsub * 32;

  __shared__ char smem[65536];
  // per half: hbase = half*32768; buf0 = +0 (K 8K | V 8K), buf1 = +16384.
  // Q (16K) staged in half0's buf1 [16384:32768), freed after qf regs loaded.
  char* hbase = smem + half * 32768;
  char* Qst = smem + 16384;

  const size_t qkbase = (size_t)b * Ss * Dd + (size_t)h * HDd;
  const f16* Vtb = Vt + (size_t)(b * Hh + h) * HDd * Ss;   // rows d (stride S), cols s
  const int sr = l >> 3, ss = l & 7;
  const int scol = ((ss ^ sr) << 3);           // pre-swizzled source col (f16 elems)

  // stage Q (16 chunks over 8 waves) + this half's tile 0 into buf0
  for (int c = 0; c < 2; c++) {
    int chunk = w * 2 + c, r = chunk * 8 + sr;
    gll16(Qp + qkbase + (size_t)(q0 + r) * Dd + scol, Qst + chunk * 1024);
  }
  const int kt0 = half * 16;                   // first absolute tile of this half
  for (int c = 0; c < 2; c++) {
    int chunk = wsub * 2 + c, r = chunk * 8 + sr;
    gll16(Kp + qkbase + (size_t)(kt0 * 64 + r) * Dd + scol, hbase + chunk * 1024);
    gll16(Vtb + (size_t)r * Ss + kt0 * 64 + scol, hbase + 8192 + chunk * 1024);
  }
  __syncthreads();

  f16x8 qf[4];   // B-frag: col q = wq+lo, k(=d) = 16c + 8*hi + e
#pragma unroll
  for (int c = 0; c < 4; c++)
    qf[c] = *(const f16x8*)(Qst + lds_byte(wq + lo, 2 * c + hi));
  __syncthreads();   // all waves' Q reads done before buf1 prefetch overwrites it

  f32x16 accO0 = {0}, accO1 = {0};             // O^T[d][q]: q = lo, d-tiles 0-31 / 32-63
  float m_run = -1e30f, l_run = 0.f;           // per-lane; l covers this lane's k subset
  const u32* mrow = mbits + (size_t)(b * Ss + q0 + wq + lo) * 64;

  for (int it = 0; it < 16; it++) {
    const int kt = kt0 + it;
    if (it) __syncthreads();                   // cur-buf loads drained; other buf free
    char* bufc = hbase + (it & 1) * 16384;
    if (it < 15) {
      char* bufn = hbase + ((it + 1) & 1) * 16384;
      const int k0n = (kt + 1) * 64;
      for (int c = 0; c < 2; c++) {
        int chunk = wsub * 2 + c, r = chunk * 8 + sr;
        gll16(Kp + qkbase + (size_t)(k0n + r) * Dd + scol, bufn + chunk * 1024);
        gll16(Vtb + (size_t)r * Ss + k0n + scol, bufn + 8192 + chunk * 1024);
      }
    }
    const char* Kb = bufc;
    const char* Vb = bufc + 8192;

    // QK^T (swapped): s0 = S^T rows k0..31, s1 = rows k32..63; col q = lo
    f32x16 s0 = {0}, s1 = {0};
    __builtin_amdgcn_s_setprio(1);
#pragma unroll
    for (int c = 0; c < 4; c++) {
      f16x8 kf0 = *(const f16x8*)(Kb + lds_byte(lo, 2 * c + hi));
      f16x8 kf1 = *(const f16x8*)(Kb + lds_byte(32 + lo, 2 * c + hi));
      s0 = __builtin_amdgcn_mfma_f32_32x32x16_f16(kf0, qf[c], s0, 0, 0, 0);
      s1 = __builtin_amdgcn_mfma_f32_32x32x16_f16(kf1, qf[c], s1, 0, 0, 0);
    }
    __builtin_amdgcn_s_setprio(0);

    // ---- online softmax, exp2 domain, defer-max ----
    uint2v mw = *(const uint2v*)(mrow + kt * 2);
    u32 wa = mw.x >> (hi << 2);                // this lane's k-bits start at 4*hi
    u32 wb = mw.y >> (hi << 2);

    float x0 = fmaxf(s0[0], s1[0]), x1 = fmaxf(s0[1], s1[1]);
    float x2 = fmaxf(s0[2], s1[2]), x3 = fmaxf(s0[3], s1[3]);
#pragma unroll
    for (int r = 4; r < 16; r += 4) {
      x0 = fmaxf(x0, fmaxf(s0[r],     s1[r]));
      x1 = fmaxf(x1, fmaxf(s0[r + 1], s1[r + 1]));
      x2 = fmaxf(x2, fmaxf(s0[r + 2], s1[r + 2]));
      x3 = fmaxf(x3, fmaxf(s0[r + 3], s1[r + 3]));
    }
    float pm = fmaxf(fmaxf(x0, x1), fmaxf(x2, x3));

    float mn;
    if (__all(pm <= m_run + 11.5f)) {
      mn = m_run;                              // deferred: p bounded by 2^11.5
    } else {
      pm = fmaxf(pm, __shfl_xor(pm, 32));      // per-q max across hi halves
      mn = fmaxf(m_run, pm);
      const float so = ex2(m_run - mn);
      m_run = mn;
      l_run *= so;
      accO0 *= so; accO1 *= so;
    }

    float racc = 0.f;
#pragma unroll
    for (int r = 0; r < 16; r++) {
      const int kk = (r & 3) + 8 * (r >> 2);   // + 4*hi already shifted out of wa/wb
      u32 ma = (u32)(((int)(wa << (31 - kk))) >> 31);
      u32 mb = (u32)(((int)(wb << (31 - kk))) >> 31);
      float e0 = __uint_as_float(__float_as_uint(ex2(s0[r] - mn)) & ma);
      float e1 = __uint_as_float(__float_as_uint(ex2(s1[r] - mn)) & mb);
      s0[r] = e0; s1[r] = e1;
      racc += e0 + e1;
    }
    l_run += racc;                             // per-lane partial; cross-lane at end

    // ---- P -> f16 A/B-frags via cvt_pkrtz + permlane32_swap (no LDS) ----
    u32 pw[16];
#pragma unroll
    for (int j = 0; j < 8; j++) {
      H2U a, c;
      a.h = __builtin_amdgcn_cvt_pkrtz(s0[2 * j], s0[2 * j + 1]);
      c.h = __builtin_amdgcn_cvt_pkrtz(s1[2 * j], s1[2 * j + 1]);
      pw[j] = a.u; pw[8 + j] = c.u;
    }
#pragma unroll
    for (int c = 0; c < 4; c++) {
      asm volatile("v_permlane32_swap_b32 %0, %1" : "+v"(pw[4 * c]), "+v"(pw[4 * c + 2]));
      asm volatile("v_permlane32_swap_b32 %0, %1" : "+v"(pw[4 * c + 1]), "+v"(pw[4 * c + 3]));
    }

    // ---- PV: O^T[d][q] += Vt[d][k] * P[q][k] ----
    __builtin_amdgcn_s_setprio(1);
#pragma unroll
    for (int c = 0; c < 4; c++) {
      union { u32 u[4]; f16x8 v; } pu;
      pu.u[0] = pw[4 * c]; pu.u[1] = pw[4 * c + 1];
      pu.u[2] = pw[4 * c + 2]; pu.u[3] = pw[4 * c + 3];
      f16x8 vf0 = *(const f16x8*)(Vb + lds_byte(lo, 2 * c + hi));
      f16x8 vf1 = *(const f16x8*)(Vb + lds_byte(32 + lo, 2 * c + hi));
      accO0 = __builtin_amdgcn_mfma_f32_32x32x16_f16(vf0, pu.v, accO0, 0, 0, 0);
      accO1 = __builtin_amdgcn_mfma_f32_32x32x16_f16(vf1, pu.v, accO1, 0, 0, 0);
    }
    __builtin_amdgcn_s_setprio(0);
  }

  // ---- merge halves (m-aware, per-lane); stride 35 floats (odd -> conflict-free) ----
  __syncthreads();
  float* mg = (float*)smem;                    // 256 lanes x 35 floats = 35840 B
  if (half == 1) {
    float* p = mg + (size_t)(wsub * 64 + l) * 35;
#pragma unroll
    for (int r = 0; r < 16; r++) { p[r] = accO0[r]; p[16 + r] = accO1[r]; }
    p[32] = m_run; p[33] = l_run;
  }
  __syncthreads();
  if (half == 1) return;

  const float* p = mg + (size_t)(wsub * 64 + l) * 35;
  const float mB = p[32], lB = p[33];
  const float m = fmaxf(m_run, mB);
  const float fA = ex2(m_run - m), fB = ex2(mB - m);
  float lmerged = l_run * fA + lB * fB;
#pragma unroll
  for (int r = 0; r < 16; r++) {
    accO0[r] = accO0[r] * fA + p[r] * fB;
    accO1[r] = accO1[r] * fA + p[16 + r] * fB;
  }
  const float lf = lmerged + __shfl_xor(lmerged, 32);   // combine hi=0/1 k-subsets
  const float inv = 1.0f / lf;

  // ---- epilogue: transpose O^T -> O through per-wave LDS, store ----
  char* Ot = smem + 40960 + wsub * 4096;       // per-wave 32q x 64d f16 (swizzled)
#pragma unroll
  for (int j = 0; j < 8; j++) {
    H2U pk;
    pk.h = __builtin_amdgcn_cvt_pkrtz(accO0[2 * j] * inv, accO0[2 * j + 1] * inv);
    int slot = (j >> 1);
    int addr = lo * 128 + (((slot ^ (lo & 7)) & 7) << 4) + 4 * (j & 1) + 8 * hi;
    *(u32*)(Ot + addr) = pk.u;
  }
#pragma unroll
  for (int j = 0; j < 8; j++) {
    H2U pk;
    pk.h = __builtin_amdgcn_cvt_pkrtz(accO1[2 * j] * inv, accO1[2 * j + 1] * inv);
    int slot = (j >> 1) + 4;
    int addr = lo * 128 + (((slot ^ (lo & 7)) & 7) << 4) + 4 * (j & 1) + 8 * hi;
    *(u32*)(Ot + addr) = pk.u;
  }
  asm volatile("s_waitcnt lgkmcnt(0)" ::: "memory");   // same-wave cross-lane LDS visibility
  {
    const int q = l >> 1, halfq = l & 1;
    f16* gbase = outp + qkbase + (size_t)(q0 + wq + q) * Dd + halfq * 32;
#pragma unroll
    for (int c = 0; c < 4; c++) {
      int byte = q * 128 + ((((halfq * 4 + c) ^ (q & 7)) & 7) << 4);
      f16x8 v = *(const f16x8*)(Ot + byte);
      *(f16x8*)(gbase + c * 8) = v;
    }
  }
}

// ---------------- launch ----------------
extern "C" void kernel_launch(void* const* d_in, const int* in_sizes, int n_in,
                              void* d_out, int out_size, void* d_ws, size_t ws_size,
                              hipStream_t stream) {
  const float* query = (const float*)d_in[0];
  const float* key_  = (const float*)d_in[1];
  const float* value = (const float*)d_in[2];
  const int*   mask  = (const int*)d_in[3];
  const float* Wq = (const float*)d_in[4];
  const float* bq = (const float*)d_in[5];
  const float* Wk = (const float*)d_in[6];
  const float* bk = (const float*)d_in[7];
  const float* Wv = (const float*)d_in[8];
  const float* bv = (const float*)d_in[9];
  const float* Wo = (const float*)d_in[10];
  const float* bo = (const float*)d_in[11];

  char* ws = (char*)d_ws;
  f16* X   = (f16*)(ws + OFF_X);
  f16* Wt  = (f16*)(ws + OFF_WT);
  f16* QKV = (f16*)(ws + OFF_QKV);
  f16* ATT = (f16*)(ws + OFF_ATT);
  unsigned* MB = (unsigned*)(ws + OFF_MB);

  prep<<<dim3(32768 + 4096 + 12288), 256, 0, stream>>>(mask, MB, query, key_, value,
                                                       Wq, Wk, Wv, Wo, Wt, X);
  gemm_qkv<<<dim3(768), 256, 0, stream>>>(X, Wt, bq, bk, bv, QKV);
  attn_fused<<<dim3(512), 512, 0, stream>>>(QKV, QKV + (size_t)M_ROWS * Dd,
                                            QKV + 2 * (size_t)M_ROWS * Dd, MB, ATT);
  gemm_out<<<dim3(256), 256, 0, stream>>>(ATT, Wt + 3 * (size_t)Dd * Dd, bo, (float*)d_out);
}

// Round 17
// 143.492 us; speedup vs baseline: 1.0267x; 1.0267x over previous
//
#include <hip/hip_runtime.h>
#include <stdint.h>

typedef _Float16 f16;
typedef _Float16 f16x4 __attribute__((ext_vector_type(4)));
typedef _Float16 f16x8 __attribute__((ext_vector_type(8)));
typedef __fp16 hf16x2 __attribute__((ext_vector_type(2)));   // cvt_pkrtz return type
typedef float f32x4 __attribute__((ext_vector_type(4)));
typedef float f32x16 __attribute__((ext_vector_type(16)));
typedef unsigned u32;
typedef unsigned uint2v __attribute__((ext_vector_type(2)));

static constexpr int Bb = 2, Ss = 2048, Dd = 1024, Hh = 16, HDd = 64;
static constexpr int M_ROWS = Bb * Ss; // 4096

// ---- workspace layout (bytes) ----
static constexpr size_t OFF_WT  = 24ull << 20;             // WtQ..WtO f16: 4 * 2 MiB
static constexpr size_t OFF_QKV = 32ull << 20;             // Q,K row-major; V transposed [b][h][d][s]
static constexpr size_t OFF_ATT = 56ull << 20;             // attn f16: 8 MiB
static constexpr size_t OFF_MB  = 64ull << 20;             // mask bits: 1 MiB

__device__ __forceinline__ void gll16(const void* g, void* l) {
  __builtin_amdgcn_global_load_lds((__attribute__((address_space(1))) const void*)g,
                                   (__attribute__((address_space(3))) void*)l, 16, 0, 0);
}

// [rows][64 f16] tile (row = 128 B): byte addr of 16B slot `slot`, XOR-swizzled.
__device__ __forceinline__ int lds_byte(int row, int slot) {
  return row * 128 + (((slot ^ (row & 7)) & 7) << 4);
}

// [rows][32 f16] tile (row = 64 B): byte addr of 16B slot `slot`, XOR-swizzled.
__device__ __forceinline__ int lds_byte32(int row, int slot) {
  return row * 64 + (((slot ^ (row & 3)) & 3) << 4);
}

// raw v_exp_f32 (input already in log2 domain)
__device__ __forceinline__ float ex2(float x) {
  float r; asm("v_exp_f32 %0, %1" : "=v"(r) : "v"(x)); return r;
}

union H2U { hf16x2 h; u32 u; };

// ---------------- prep: pack mask bits + transpose/convert weights ----------------
__global__ __launch_bounds__(256) void prep(const int* __restrict__ mask,
                                            unsigned* __restrict__ bits,
                                            const float* __restrict__ wq,
                                            const float* __restrict__ wk,
                                            const float* __restrict__ wv,
                                            const float* __restrict__ wo,
                                            f16* __restrict__ wt) {
  const int bid = blockIdx.x;
  __shared__ float t[32][33];
  if (bid < 32768) {
    size_t i = (size_t)bid * 256 + threadIdx.x;    // one thread per mask int
    int v = mask[i];
    unsigned long long bm = __ballot(v != 0);
    if ((threadIdx.x & 63) == 0) {
      size_t w = i >> 5;
      bits[w]     = (unsigned)bm;
      bits[w + 1] = (unsigned)(bm >> 32);
    }
  } else {
    const int wb = bid - 32768;                    // z*1024 + by*32 + bx
    const int z = wb >> 10, by = (wb >> 5) & 31, bx = wb & 31;
    const float* W = z == 0 ? wq : z == 1 ? wk : z == 2 ? wv : wo;
    f16* Wt = wt + (size_t)z * Dd * Dd;
    const int tx = threadIdx.x & 31, ty = threadIdx.x >> 5;   // (32, 8)
    const int k0 = by * 32, n0 = bx * 32;
    for (int i = 0; i < 32; i += 8) t[ty + i][tx] = W[(size_t)(k0 + ty + i) * Dd + n0 + tx];
    __syncthreads();
    for (int i = 0; i < 32; i += 8) Wt[(size_t)(n0 + ty + i) * Dd + k0 + tx] = (f16)t[tx][ty + i];
  }
}

// ---------------- QKV GEMM: BK=32, fp32-A cvt in-staging, 32KB LDS -> 3 blocks/CU ----------------
// z==0: output scaled by 0.125*log2e; z==2: output stored TRANSPOSED as Vt[b][h][d][s]
__global__ __launch_bounds__(256) void gemm_qkv(const float* __restrict__ qin,
                                                const float* __restrict__ kin,
                                                const float* __restrict__ vin,
                                                const f16* __restrict__ Btbase,
                                                const float* __restrict__ b0,
                                                const float* __restrict__ b1,
                                                const float* __restrict__ b2,
                                                f16* __restrict__ Cbase) {
  constexpr int K = Dd, N = Dd;
  const int f = blockIdx.x;                 // 0..767
  const int z = f >> 8, i = f & 255;
  const int xg = i & 7, sl = i >> 3;        // XCD-chunked m-panel map (R10)
  const int m0 = (xg * 4 + (sl >> 3)) * 128, n0 = (sl & 7) * 128;
  const float* A = z == 0 ? qin : z == 1 ? kin : vin;
  const f16* Bt = Btbase + (size_t)z * N * K;
  const float* bias = z == 0 ? b0 : z == 1 ? b1 : b2;

  __shared__ char smem[32768];              // bufA[2] @ 0,8192 ; bufB[2] @ 16384,24576
  const int tid = threadIdx.x, l = tid & 63, w = tid >> 6;   // w 0..3
  const int li = l & 15, gq = l >> 4;
  const int wm = (w >> 1) * 64, wn = (w & 1) * 64;
  const int sr = l >> 2, ss = l & 3;        // BK=32 staging: row-in-chunk 0..15, slot 0..3
  const int scol = ((ss ^ (sr & 3)) << 3);  // pre-swizzled source col (elems)

  f32x4 acc[4][4];
  for (int mi = 0; mi < 4; mi++)
    for (int ni = 0; ni < 4; ni++) acc[mi][ni] = f32x4{0.f, 0.f, 0.f, 0.f};

  float4 a0[2], a1[2];
  // ---- prologue: stage tile 0 into buf0 ----
#pragma unroll
  for (int c = 0; c < 2; c++) {
    int chunk = w * 2 + c, r = chunk * 16 + sr;
    gll16(Bt + (size_t)(n0 + r) * K + scol, smem + 16384 + chunk * 1024);
    const float* src = A + (size_t)(m0 + r) * K + scol;
    a0[c] = *(const float4*)src; a1[c] = *(const float4*)(src + 4);
  }
#pragma unroll
  for (int c = 0; c < 2; c++) {
    int chunk = w * 2 + c;
    H2U h0, h1, h2, h3;
    h0.h = __builtin_amdgcn_cvt_pkrtz(a0[c].x, a0[c].y);
    h1.h = __builtin_amdgcn_cvt_pkrtz(a0[c].z, a0[c].w);
    h2.h = __builtin_amdgcn_cvt_pkrtz(a1[c].x, a1[c].y);
    h3.h = __builtin_amdgcn_cvt_pkrtz(a1[c].z, a1[c].w);
    union { u32 uu[4]; f16x8 v8; } pk;
    pk.uu[0] = h0.u; pk.uu[1] = h1.u; pk.uu[2] = h2.u; pk.uu[3] = h3.u;
    *(f16x8*)(smem + chunk * 1024 + l * 16) = pk.v8;
  }

  for (int it = 0; it < 32; it++) {
    __syncthreads();                        // drains stage(it); frees buf[(it+1)&1]
    char* Asc = smem + (it & 1) * 8192;
    char* Bsc = smem + 16384 + (it & 1) * 8192;
    if (it < 31) {                          // issue stage(it+1): flies under compute(it)
      char* Bsn = smem + 16384 + ((it + 1) & 1) * 8192;
      const int kn = (it + 1) * 32;
#pragma unroll
      for (int c = 0; c < 2; c++) {
        int chunk = w * 2 + c, r = chunk * 16 + sr;
        gll16(Bt + (size_t)(n0 + r) * K + kn + scol, Bsn + chunk * 1024);
        const float* src = A + (size_t)(m0 + r) * K + kn + scol;
        a0[c] = *(const float4*)src; a1[c] = *(const float4*)(src + 4);
      }
    }
    f16x8 af[4], bf[4];
#pragma unroll
    for (int ii = 0; ii < 4; ii++) {
      af[ii] = *(const f16x8*)(Asc + lds_byte32(wm + ii * 16 + li, gq));
      bf[ii] = *(const f16x8*)(Bsc + lds_byte32(wn + ii * 16 + li, gq));
    }
#pragma unroll
    for (int mi = 0; mi < 4; mi++)
#pragma unroll
      for (int ni = 0; ni < 4; ni++)
        acc[mi][ni] = __builtin_amdgcn_mfma_f32_16x16x32_f16(af[mi], bf[ni], acc[mi][ni], 0, 0, 0);
    if (it < 31) {                          // A cvt + ds_write after MFMA (loads drained by now)
      char* Asn = smem + ((it + 1) & 1) * 8192;
#pragma unroll
      for (int c = 0; c < 2; c++) {
        int chunk = w * 2 + c;
        H2U h0, h1, h2, h3;
        h0.h = __builtin_amdgcn_cvt_pkrtz(a0[c].x, a0[c].y);
        h1.h = __builtin_amdgcn_cvt_pkrtz(a0[c].z, a0[c].w);
        h2.h = __builtin_amdgcn_cvt_pkrtz(a1[c].x, a1[c].y);
        h3.h = __builtin_amdgcn_cvt_pkrtz(a1[c].z, a1[c].w);
        union { u32 uu[4]; f16x8 v8; } pk;
        pk.uu[0] = h0.u; pk.uu[1] = h1.u; pk.uu[2] = h2.u; pk.uu[3] = h3.u;
        *(f16x8*)(Asn + chunk * 1024 + l * 16) = pk.v8;
      }
    }
  }

  const float scl = (z == 0) ? 0.18033688011112042f : 1.0f;   // 0.125*log2e
  if (z == 2) {
    // transposed V: Vt[(b*16+h)*64 + d][s], packed f16x4 along s
    f16* Vt = Cbase + (size_t)2 * M_ROWS * N;
#pragma unroll
    for (int mi = 0; mi < 4; mi++)
#pragma unroll
      for (int ni = 0; ni < 4; ni++) {
        const int col = n0 + wn + ni * 16 + li;        // h*64 + d
        const int r0  = m0 + wm + mi * 16 + gq * 4;    // global s index (4-aligned)
        const int bb_ = r0 >> 11, s = r0 & 2047;
        const float bv = bias[col];
        f16x4 pk;
#pragma unroll
        for (int j = 0; j < 4; j++) pk[j] = (f16)(acc[mi][ni][j] + bv);
        *(f16x4*)(Vt + ((size_t)(bb_ * Hh) << 17) + (size_t)col * Ss + s) = pk;
      }
  } else {
    for (int mi = 0; mi < 4; mi++)
      for (int ni = 0; ni < 4; ni++) {
        const int r0  = m0 + wm + mi * 16 + gq * 4;
        const int col = n0 + wn + ni * 16 + li;
        const float bb = bias[col];
#pragma unroll
        for (int j = 0; j < 4; j++) {
          float val = (acc[mi][ni][j] + bb) * scl;
          Cbase[(size_t)z * M_ROWS * N + (size_t)(r0 + j) * N + col] = (f16)val;
        }
      }
  }
}

// ---------------- output GEMM: 2-phase double-buffered, f16 A (attn), fp32 out ----------------
__global__ __launch_bounds__(256) void gemm_out(const f16* __restrict__ A,
                                                const f16* __restrict__ Bt,
                                                const float* __restrict__ bias,
                                                float* __restrict__ C) {
  constexpr int K = Dd, N = Dd;
  const int f = blockIdx.x;                 // 0..255
  const int xg = f & 7, sl = f >> 3;
  const int m0 = (xg * 4 + (sl >> 3)) * 128, n0 = (sl & 7) * 128;
  __shared__ char smem[65536];              // buf[2] x (As 16K | Bs 16K)
  const int tid = threadIdx.x, l = tid & 63, w = tid >> 6;
  const int li = l & 15, gq = l >> 4;
  const int wm = (w >> 1) * 64, wn = (w & 1) * 64;
  const int sr = l >> 3, ss = l & 7;
  const int scol = ((ss ^ sr) << 3);

  f32x4 acc[4][4];
  for (int mi = 0; mi < 4; mi++)
    for (int ni = 0; ni < 4; ni++) acc[mi][ni] = f32x4{0.f, 0.f, 0.f, 0.f};

  // prologue: stage tile 0 into buf0
#pragma unroll
  for (int c = 0; c < 4; c++) {
    int chunk = w * 4 + c, r = chunk * 8 + sr;
    gll16(A  + (size_t)(m0 + r) * K + scol, smem + chunk * 1024);
    gll16(Bt + (size_t)(n0 + r) * K + scol, smem + 16384 + chunk * 1024);
  }

  int cur = 0;
  for (int it = 0; it < 16; it++) {
    __syncthreads();
    char* Asc = smem + cur * 32768;
    char* Bsc = Asc + 16384;
    if (it < 15) {
      char* Asn = smem + (cur ^ 1) * 32768;
      const int kn = (it + 1) * 64;
#pragma unroll
      for (int c = 0; c < 4; c++) {
        int chunk = w * 4 + c, r = chunk * 8 + sr;
        gll16(A  + (size_t)(m0 + r) * K + kn + scol, Asn + chunk * 1024);
        gll16(Bt + (size_t)(n0 + r) * K + kn + scol, Asn + 16384 + chunk * 1024);
      }
    }
#pragma unroll
    for (int ks = 0; ks < 2; ks++) {
      f16x8 af[4], bf[4];
#pragma unroll
      for (int ii = 0; ii < 4; ii++) {
        af[ii] = *(const f16x8*)(Asc + lds_byte(wm + ii * 16 + li, ks * 4 + gq));
        bf[ii] = *(const f16x8*)(Bsc + lds_byte(wn + ii * 16 + li, ks * 4 + gq));
      }
#pragma unroll
      for (int mi = 0; mi < 4; mi++)
#pragma unroll
        for (int ni = 0; ni < 4; ni++)
          acc[mi][ni] = __builtin_amdgcn_mfma_f32_16x16x32_f16(af[mi], bf[ni], acc[mi][ni], 0, 0, 0);
    }
    cur ^= 1;
  }

  for (int mi = 0; mi < 4; mi++)
    for (int ni = 0; ni < 4; ni++) {
      const int r0  = m0 + wm + mi * 16 + gq * 4;
      const int col = n0 + wn + ni * 16 + li;
      const float bb = bias[col];
#pragma unroll
      for (int j = 0; j < 4; j++)
        C[(size_t)(r0 + j) * N + col] = acc[mi][ni][j] + bb;
    }
}

// ---------------- fused attention (split-k, 8 waves, defer-max exp2 softmax) — proven ----------------
__global__ __launch_bounds__(512, 4) void attn_fused(const f16* __restrict__ Qp,
                                                     const f16* __restrict__ Kp,
                                                     const f16* __restrict__ Vt,
                                                     const u32* __restrict__ mbits,
                                                     f16* __restrict__ outp) {
  // XCD-aware decode: all 16 q-tiles of one (b,h) land on one XCD for K/V L2 reuse
  const int flat = blockIdx.x;                 // 0..511
  const int xcd = flat & 7, jj = flat >> 3;    // jj 0..63
  const int qt = jj & 15;
  const int hb = xcd * 4 + (jj >> 4);          // 0..31
  const int h = hb & 15, b = hb >> 4;

  const int tid = threadIdx.x, l = tid & 63, w = tid >> 6;   // w 0..7
  const int lo = l & 31, hi = l >> 5;
  const int half = w >> 2, wsub = w & 3;
  const int q0 = qt * 128, wq = wsub * 32;

  __shared__ char smem[65536];
  // per half: hbase = half*32768; buf0 = +0 (K 8K | V 8K), buf1 = +16384.
  // Q (16K) staged in half0's buf1 [16384:32768), freed after qf regs loaded.
  char* hbase = smem + half * 32768;
  char* Qst = smem + 16384;

  const size_t qkbase = (size_t)b * Ss * Dd + (size_t)h * HDd;
  const f16* Vtb = Vt + (size_t)(b * Hh + h) * HDd * Ss;   // rows d (stride S), cols s
  const int sr = l >> 3, ss = l & 7;
  const int scol = ((ss ^ sr) << 3);           // pre-swizzled source col (f16 elems)

  // stage Q (16 chunks over 8 waves) + this half's tile 0 into buf0
  for (int c = 0; c < 2; c++) {
    int chunk = w * 2 + c, r = chunk * 8 + sr;
    gll16(Qp + qkbase + (size_t)(q0 + r) * Dd + scol, Qst + chunk * 1024);
  }
  const int kt0 = half * 16;                   // first absolute tile of this half
  for (int c = 0; c < 2; c++) {
    int chunk = wsub * 2 + c, r = chunk * 8 + sr;
    gll16(Kp + qkbase + (size_t)(kt0 * 64 + r) * Dd + scol, hbase + chunk * 1024);
    gll16(Vtb + (size_t)r * Ss + kt0 * 64 + scol, hbase + 8192 + chunk * 1024);
  }
  __syncthreads();

  f16x8 qf[4];   // B-frag: col q = wq+lo, k(=d) = 16c + 8*hi + e
#pragma unroll
  for (int c = 0; c < 4; c++)
    qf[c] = *(const f16x8*)(Qst + lds_byte(wq + lo, 2 * c + hi));
  __syncthreads();   // all waves' Q reads done before buf1 prefetch overwrites it

  f32x16 accO0 = {0}, accO1 = {0};             // O^T[d][q]: q = lo, d-tiles 0-31 / 32-63
  float m_run = -1e30f, l_run = 0.f;           // per-lane; l covers this lane's k subset
  const u32* mrow = mbits + (size_t)(b * Ss + q0 + wq + lo) * 64;

  for (int it = 0; it < 16; it++) {
    const int kt = kt0 + it;
    if (it) __syncthreads();                   // cur-buf loads drained; other buf free
    char* bufc = hbase + (it & 1) * 16384;
    if (it < 15) {
      char* bufn = hbase + ((it + 1) & 1) * 16384;
      const int k0n = (kt + 1) * 64;
      for (int c = 0; c < 2; c++) {
        int chunk = wsub * 2 + c, r = chunk * 8 + sr;
        gll16(Kp + qkbase + (size_t)(k0n + r) * Dd + scol, bufn + chunk * 1024);
        gll16(Vtb + (size_t)r * Ss + k0n + scol, bufn + 8192 + chunk * 1024);
      }
    }
    const char* Kb = bufc;
    const char* Vb = bufc + 8192;

    // QK^T (swapped): s0 = S^T rows k0..31, s1 = rows k32..63; col q = lo
    f32x16 s0 = {0}, s1 = {0};
    __builtin_amdgcn_s_setprio(1);
#pragma unroll
    for (int c = 0; c < 4; c++) {
      f16x8 kf0 = *(const f16x8*)(Kb + lds_byte(lo, 2 * c + hi));
      f16x8 kf1 = *(const f16x8*)(Kb + lds_byte(32 + lo, 2 * c + hi));
      s0 = __builtin_amdgcn_mfma_f32_32x32x16_f16(kf0, qf[c], s0, 0, 0, 0);
      s1 = __builtin_amdgcn_mfma_f32_32x32x16_f16(kf1, qf[c], s1, 0, 0, 0);
    }
    __builtin_amdgcn_s_setprio(0);

    // ---- online softmax, exp2 domain, defer-max ----
    uint2v mw = *(const uint2v*)(mrow + kt * 2);
    u32 wa = mw.x >> (hi << 2);                // this lane's k-bits start at 4*hi
    u32 wb = mw.y >> (hi << 2);

    float x0 = fmaxf(s0[0], s1[0]), x1 = fmaxf(s0[1], s1[1]);
    float x2 = fmaxf(s0[2], s1[2]), x3 = fmaxf(s0[3], s1[3]);
#pragma unroll
    for (int r = 4; r < 16; r += 4) {
      x0 = fmaxf(x0, fmaxf(s0[r],     s1[r]));
      x1 = fmaxf(x1, fmaxf(s0[r + 1], s1[r + 1]));
      x2 = fmaxf(x2, fmaxf(s0[r + 2], s1[r + 2]));
      x3 = fmaxf(x3, fmaxf(s0[r + 3], s1[r + 3]));
    }
    float pm = fmaxf(fmaxf(x0, x1), fmaxf(x2, x3));

    float mn;
    if (__all(pm <= m_run + 11.5f)) {
      mn = m_run;                              // deferred: p bounded by 2^11.5
    } else {
      pm = fmaxf(pm, __shfl_xor(pm, 32));      // per-q max across hi halves
      mn = fmaxf(m_run, pm);
      const float so = ex2(m_run - mn);
      m_run = mn;
      l_run *= so;
      accO0 *= so; accO1 *= so;
    }

    float racc = 0.f;
#pragma unroll
    for (int r = 0; r < 16; r++) {
      const int kk = (r & 3) + 8 * (r >> 2);   // + 4*hi already shifted out of wa/wb
      u32 ma = (u32)(((int)(wa << (31 - kk))) >> 31);
      u32 mb = (u32)(((int)(wb << (31 - kk))) >> 31);
      float e0 = __uint_as_float(__float_as_uint(ex2(s0[r] - mn)) & ma);
      float e1 = __uint_as_float(__float_as_uint(ex2(s1[r] - mn)) & mb);
      s0[r] = e0; s1[r] = e1;
      racc += e0 + e1;
    }
    l_run += racc;                             // per-lane partial; cross-lane at end

    // ---- P -> f16 A/B-frags via cvt_pkrtz + permlane32_swap (no LDS) ----
    u32 pw[16];
#pragma unroll
    for (int j = 0; j < 8; j++) {
      H2U a, c;
      a.h = __builtin_amdgcn_cvt_pkrtz(s0[2 * j], s0[2 * j + 1]);
      c.h = __builtin_amdgcn_cvt_pkrtz(s1[2 * j], s1[2 * j + 1]);
      pw[j] = a.u; pw[8 + j] = c.u;
    }
#pragma unroll
    for (int c = 0; c < 4; c++) {
      asm volatile("v_permlane32_swap_b32 %0, %1" : "+v"(pw[4 * c]), "+v"(pw[4 * c + 2]));
      asm volatile("v_permlane32_swap_b32 %0, %1" : "+v"(pw[4 * c + 1]), "+v"(pw[4 * c + 3]));
    }

    // ---- PV: O^T[d][q] += Vt[d][k] * P[q][k] ----
    __builtin_amdgcn_s_setprio(1);
#pragma unroll
    for (int c = 0; c < 4; c++) {
      union { u32 u[4]; f16x8 v; } pu;
      pu.u[0] = pw[4 * c]; pu.u[1] = pw[4 * c + 1];
      pu.u[2] = pw[4 * c + 2]; pu.u[3] = pw[4 * c + 3];
      f16x8 vf0 = *(const f16x8*)(Vb + lds_byte(lo, 2 * c + hi));
      f16x8 vf1 = *(const f16x8*)(Vb + lds_byte(32 + lo, 2 * c + hi));
      accO0 = __builtin_amdgcn_mfma_f32_32x32x16_f16(vf0, pu.v, accO0, 0, 0, 0);
      accO1 = __builtin_amdgcn_mfma_f32_32x32x16_f16(vf1, pu.v, accO1, 0, 0, 0);
    }
    __builtin_amdgcn_s_setprio(0);
  }

  // ---- merge halves (m-aware, per-lane); stride 35 floats (odd -> conflict-free) ----
  __syncthreads();
  float* mg = (float*)smem;                    // 256 lanes x 35 floats = 35840 B
  if (half == 1) {
    float* p = mg + (size_t)(wsub * 64 + l) * 35;
#pragma unroll
    for (int r = 0; r < 16; r++) { p[r] = accO0[r]; p[16 + r] = accO1[r]; }
    p[32] = m_run; p[33] = l_run;
  }
  __syncthreads();
  if (half == 1) return;

  const float* p = mg + (size_t)(wsub * 64 + l) * 35;
  const float mB = p[32], lB = p[33];
  const float m = fmaxf(m_run, mB);
  const float fA = ex2(m_run - m), fB = ex2(mB - m);
  float lmerged = l_run * fA + lB * fB;
#pragma unroll
  for (int r = 0; r < 16; r++) {
    accO0[r] = accO0[r] * fA + p[r] * fB;
    accO1[r] = accO1[r] * fA + p[16 + r] * fB;
  }
  const float lf = lmerged + __shfl_xor(lmerged, 32);   // combine hi=0/1 k-subsets
  const float inv = 1.0f / lf;

  // ---- epilogue: transpose O^T -> O through per-wave LDS, store ----
  char* Ot = smem + 40960 + wsub * 4096;       // per-wave 32q x 64d f16 (swizzled)
#pragma unroll
  for (int j = 0; j < 8; j++) {
    H2U pk;
    pk.h = __builtin_amdgcn_cvt_pkrtz(accO0[2 * j] * inv, accO0[2 * j + 1] * inv);
    int slot = (j >> 1);
    int addr = lo * 128 + (((slot ^ (lo & 7)) & 7) << 4) + 4 * (j & 1) + 8 * hi;
    *(u32*)(Ot + addr) = pk.u;
  }
#pragma unroll
  for (int j = 0; j < 8; j++) {
    H2U pk;
    pk.h = __builtin_amdgcn_cvt_pkrtz(accO1[2 * j] * inv, accO1[2 * j + 1] * inv);
    int slot = (j >> 1) + 4;
    int addr = lo * 128 + (((slot ^ (lo & 7)) & 7) << 4) + 4 * (j & 1) + 8 * hi;
    *(u32*)(Ot + addr) = pk.u;
  }
  asm volatile("s_waitcnt lgkmcnt(0)" ::: "memory");   // same-wave cross-lane LDS visibility
  {
    const int q = l >> 1, halfq = l & 1;
    f16* gbase = outp + qkbase + (size_t)(q0 + wq + q) * Dd + halfq * 32;
#pragma unroll
    for (int c = 0; c < 4; c++) {
      int byte = q * 128 + ((((halfq * 4 + c) ^ (q & 7)) & 7) << 4);
      f16x8 v = *(const f16x8*)(Ot + byte);
      *(f16x8*)(gbase + c * 8) = v;
    }
  }
}

// ---------------- launch ----------------
extern "C" void kernel_launch(void* const* d_in, const int* in_sizes, int n_in,
                              void* d_out, int out_size, void* d_ws, size_t ws_size,
                              hipStream_t stream) {
  const float* query = (const float*)d_in[0];
  const float* key_  = (const float*)d_in[1];
  const float* value = (const float*)d_in[2];
  const int*   mask  = (const int*)d_in[3];
  const float* Wq = (const float*)d_in[4];
  const float* bq = (const float*)d_in[5];
  const float* Wk = (const float*)d_in[6];
  const float* bk = (const float*)d_in[7];
  const float* Wv = (const float*)d_in[8];
  const float* bv = (const float*)d_in[9];
  const float* Wo = (const float*)d_in[10];
  const float* bo = (const float*)d_in[11];

  char* ws = (char*)d_ws;
  f16* Wt  = (f16*)(ws + OFF_WT);
  f16* QKV = (f16*)(ws + OFF_QKV);
  f16* ATT = (f16*)(ws + OFF_ATT);
  unsigned* MB = (unsigned*)(ws + OFF_MB);

  prep<<<dim3(32768 + 4096), 256, 0, stream>>>(mask, MB, Wq, Wk, Wv, Wo, Wt);
  gemm_qkv<<<dim3(768), 256, 0, stream>>>(query, key_, value, Wt, bq, bk, bv, QKV);
  attn_fused<<<dim3(512), 512, 0, stream>>>(QKV, QKV + (size_t)M_ROWS * Dd,
                                            QKV + 2 * (size_t)M_ROWS * Dd, MB, ATT);
  gemm_out<<<dim3(256), 256, 0, stream>>>(ATT, Wt + 3 * (size_t)Dd * Dd, bo, (float*)d_out);
}

// Round 18
// 135.027 us; speedup vs baseline: 1.0911x; 1.0627x over previous
//
#include <hip/hip_runtime.h>
#include <stdint.h>

typedef _Float16 f16;
typedef _Float16 f16x4 __attribute__((ext_vector_type(4)));
typedef _Float16 f16x8 __attribute__((ext_vector_type(8)));
typedef __fp16 hf16x2 __attribute__((ext_vector_type(2)));   // cvt_pkrtz return type
typedef float f32x4 __attribute__((ext_vector_type(4)));
typedef float f32x16 __attribute__((ext_vector_type(16)));
typedef unsigned u32;
typedef unsigned uint2v __attribute__((ext_vector_type(2)));

static constexpr int Bb = 2, Ss = 2048, Dd = 1024, Hh = 16, HDd = 64;
static constexpr int M_ROWS = Bb * Ss; // 4096

// ---- workspace layout (bytes) ----
static constexpr size_t OFF_WT  = 24ull << 20;             // WtQ..WtO f16: 4 * 2 MiB
static constexpr size_t OFF_QKV = 32ull << 20;             // Q,K row-major; V transposed [b][h][d][s]
static constexpr size_t OFF_ATT = 56ull << 20;             // attn f16: 8 MiB
static constexpr size_t OFF_MB  = 64ull << 20;             // mask bits: 1 MiB

__device__ __forceinline__ void gll16(const void* g, void* l) {
  __builtin_amdgcn_global_load_lds((__attribute__((address_space(1))) const void*)g,
                                   (__attribute__((address_space(3))) void*)l, 16, 0, 0);
}

// [rows][64 f16] tile (row = 128 B): byte addr of 16B slot `slot`, XOR-swizzled.
__device__ __forceinline__ int lds_byte(int row, int slot) {
  return row * 128 + (((slot ^ (row & 7)) & 7) << 4);
}

// raw v_exp_f32 (input already in log2 domain)
__device__ __forceinline__ float ex2(float x) {
  float r; asm("v_exp_f32 %0, %1" : "=v"(r) : "v"(x)); return r;
}

union H2U { hf16x2 h; u32 u; };

// ---------------- prep: pack mask bits + transpose/convert weights ----------------
__global__ __launch_bounds__(256) void prep(const int* __restrict__ mask,
                                            unsigned* __restrict__ bits,
                                            const float* __restrict__ wq,
                                            const float* __restrict__ wk,
                                            const float* __restrict__ wv,
                                            const float* __restrict__ wo,
                                            f16* __restrict__ wt) {
  const int bid = blockIdx.x;
  __shared__ float t[32][33];
  if (bid < 32768) {
    size_t i = (size_t)bid * 256 + threadIdx.x;    // one thread per mask int
    int v = mask[i];
    unsigned long long bm = __ballot(v != 0);
    if ((threadIdx.x & 63) == 0) {
      size_t w = i >> 5;
      bits[w]     = (unsigned)bm;
      bits[w + 1] = (unsigned)(bm >> 32);
    }
  } else {
    const int wb = bid - 32768;                    // z*1024 + by*32 + bx
    const int z = wb >> 10, by = (wb >> 5) & 31, bx = wb & 31;
    const float* W = z == 0 ? wq : z == 1 ? wk : z == 2 ? wv : wo;
    f16* Wt = wt + (size_t)z * Dd * Dd;
    const int tx = threadIdx.x & 31, ty = threadIdx.x >> 5;   // (32, 8)
    const int k0 = by * 32, n0 = bx * 32;
    for (int i = 0; i < 32; i += 8) t[ty + i][tx] = W[(size_t)(k0 + ty + i) * Dd + n0 + tx];
    __syncthreads();
    for (int i = 0; i < 32; i += 8) Wt[(size_t)(n0 + ty + i) * Dd + k0 + tx] = (f16)t[tx][ty + i];
  }
}

// ---------------- QKV GEMM: 2-iteration-deep pipeline (counted vmcnt, tri-buffer B) — R15 best ----------------
__global__ __launch_bounds__(256) void gemm_qkv(const float* __restrict__ qin,
                                                const float* __restrict__ kin,
                                                const float* __restrict__ vin,
                                                const f16* __restrict__ Btbase,
                                                const float* __restrict__ b0,
                                                const float* __restrict__ b1,
                                                const float* __restrict__ b2,
                                                f16* __restrict__ Cbase) {
  constexpr int K = Dd, N = Dd;
  const int f = blockIdx.x;                 // 0..767
  const int z = f >> 8, i = f & 255;
  const int xg = i & 7, sl = i >> 3;        // XCD-chunked m-panel map (R10)
  const int m0 = (xg * 4 + (sl >> 3)) * 128, n0 = (sl & 7) * 128;
  const float* A = z == 0 ? qin : z == 1 ? kin : vin;
  const f16* Bt = Btbase + (size_t)z * N * K;
  const float* bias = z == 0 ? b0 : z == 1 ? b1 : b2;

  __shared__ char smem[81920];              // bufA[2] @ 0,16384 ; bufB[3] @ 32768+
  const int tid = threadIdx.x, l = tid & 63, w = tid >> 6;   // w 0..3
  const int li = l & 15, gq = l >> 4;
  const int wm = (w >> 1) * 64, wn = (w & 1) * 64;
  const int sr = l >> 3, ss = l & 7;
  const int scol = ((ss ^ sr) << 3);        // pre-swizzled source col (elems)

  f32x4 acc[4][4];
  for (int mi = 0; mi < 4; mi++)
    for (int ni = 0; ni < 4; ni++) acc[mi][ni] = f32x4{0.f, 0.f, 0.f, 0.f};

  float4 a0[2][4], a1[2][4];                // two in-flight A-register sets (parity t&1)

  // ---- prologue: issue loads(0) and loads(1) (12 vm-ops each) ----
#pragma unroll
  for (int t = 0; t < 2; t++) {
    const int kt = t * 64;
#pragma unroll
    for (int c = 0; c < 4; c++) {
      int chunk = w * 4 + c, r = chunk * 8 + sr;
      gll16(Bt + (size_t)(n0 + r) * K + kt + scol, smem + 32768 + t * 16384 + chunk * 1024);
      const float* src = A + (size_t)(m0 + r) * K + kt + scol;
      a0[t][c] = *(const float4*)src;
      a1[t][c] = *(const float4*)(src + 4);
    }
  }

#pragma unroll
  for (int t = 0; t < 16; t++) {
    // [A] drain loads(t); keep loads(t+1) (12 ops) in flight
    if (t < 15) asm volatile("s_waitcnt vmcnt(12)" ::: "memory");
    else        asm volatile("s_waitcnt vmcnt(0)"  ::: "memory");

    // [B] cvt + linear ds_write A(t) into bufA[t&1]
    {
      char* bufA = smem + (t & 1) * 16384;
#pragma unroll
      for (int c = 0; c < 4; c++) {
        int chunk = w * 4 + c;
        H2U h0, h1, h2, h3;
        h0.h = __builtin_amdgcn_cvt_pkrtz(a0[t & 1][c].x, a0[t & 1][c].y);
        h1.h = __builtin_amdgcn_cvt_pkrtz(a0[t & 1][c].z, a0[t & 1][c].w);
        h2.h = __builtin_amdgcn_cvt_pkrtz(a1[t & 1][c].x, a1[t & 1][c].y);
        h3.h = __builtin_amdgcn_cvt_pkrtz(a1[t & 1][c].z, a1[t & 1][c].w);
        union { u32 uu[4]; f16x8 v8; } pk;
        pk.uu[0] = h0.u; pk.uu[1] = h1.u; pk.uu[2] = h2.u; pk.uu[3] = h3.u;
        *(f16x8*)(bufA + chunk * 1024 + l * 16) = pk.v8;
      }
    }
    asm volatile("s_waitcnt lgkmcnt(0)" ::: "memory");
    __builtin_amdgcn_s_barrier();

    // [C] issue loads(t+2): B -> bufB[(t+2)%3], A -> regs set (t&1) just freed
    if (t + 2 < 16) {
      const int tn = t + 2, kn = tn * 64;
#pragma unroll
      for (int c = 0; c < 4; c++) {
        int chunk = w * 4 + c, r = chunk * 8 + sr;
        gll16(Bt + (size_t)(n0 + r) * K + kn + scol,
              smem + 32768 + (tn % 3) * 16384 + chunk * 1024);
        const float* src = A + (size_t)(m0 + r) * K + kn + scol;
        a0[tn & 1][c] = *(const float4*)src;
        a1[tn & 1][c] = *(const float4*)(src + 4);
      }
    }
    __builtin_amdgcn_sched_barrier(0);      // pin issue before MFMA block

    // [D] MFMA(t)
    const char* Asc = smem + (t & 1) * 16384;
    const char* Bsc = smem + 32768 + (t % 3) * 16384;
#pragma unroll
    for (int ks = 0; ks < 2; ks++) {
      f16x8 af[4], bf[4];
#pragma unroll
      for (int ii = 0; ii < 4; ii++) {
        af[ii] = *(const f16x8*)(Asc + lds_byte(wm + ii * 16 + li, ks * 4 + gq));
        bf[ii] = *(const f16x8*)(Bsc + lds_byte(wn + ii * 16 + li, ks * 4 + gq));
      }
#pragma unroll
      for (int mi = 0; mi < 4; mi++)
#pragma unroll
        for (int ni = 0; ni < 4; ni++)
          acc[mi][ni] = __builtin_amdgcn_mfma_f32_16x16x32_f16(af[mi], bf[ni], acc[mi][ni], 0, 0, 0);
    }
  }

  const float scl = (z == 0) ? 0.18033688011112042f : 1.0f;   // 0.125*log2e
  if (z == 2) {
    // transposed V: Vt[(b*16+h)*64 + d][s], packed f16x4 along s
    f16* Vt = Cbase + (size_t)2 * M_ROWS * N;
#pragma unroll
    for (int mi = 0; mi < 4; mi++)
#pragma unroll
      for (int ni = 0; ni < 4; ni++) {
        const int col = n0 + wn + ni * 16 + li;        // h*64 + d
        const int r0  = m0 + wm + mi * 16 + gq * 4;    // global s index (4-aligned)
        const int bb_ = r0 >> 11, s = r0 & 2047;
        const float bv = bias[col];
        f16x4 pk;
#pragma unroll
        for (int j = 0; j < 4; j++) pk[j] = (f16)(acc[mi][ni][j] + bv);
        *(f16x4*)(Vt + ((size_t)(bb_ * Hh) << 17) + (size_t)col * Ss + s) = pk;
      }
  } else {
    for (int mi = 0; mi < 4; mi++)
      for (int ni = 0; ni < 4; ni++) {
        const int r0  = m0 + wm + mi * 16 + gq * 4;
        const int col = n0 + wn + ni * 16 + li;
        const float bb = bias[col];
#pragma unroll
        for (int j = 0; j < 4; j++) {
          float val = (acc[mi][ni][j] + bb) * scl;
          Cbase[(size_t)z * M_ROWS * N + (size_t)(r0 + j) * N + col] = (f16)val;
        }
      }
  }
}

// ---------------- output GEMM: 2-phase double-buffered, f16 A (attn), fp32 out ----------------
__global__ __launch_bounds__(256) void gemm_out(const f16* __restrict__ A,
                                                const f16* __restrict__ Bt,
                                                const float* __restrict__ bias,
                                                float* __restrict__ C) {
  constexpr int K = Dd, N = Dd;
  const int f = blockIdx.x;                 // 0..255
  const int xg = f & 7, sl = f >> 3;
  const int m0 = (xg * 4 + (sl >> 3)) * 128, n0 = (sl & 7) * 128;
  __shared__ char smem[65536];              // buf[2] x (As 16K | Bs 16K)
  const int tid = threadIdx.x, l = tid & 63, w = tid >> 6;
  const int li = l & 15, gq = l >> 4;
  const int wm = (w >> 1) * 64, wn = (w & 1) * 64;
  const int sr = l >> 3, ss = l & 7;
  const int scol = ((ss ^ sr) << 3);

  f32x4 acc[4][4];
  for (int mi = 0; mi < 4; mi++)
    for (int ni = 0; ni < 4; ni++) acc[mi][ni] = f32x4{0.f, 0.f, 0.f, 0.f};

  // prologue: stage tile 0 into buf0
#pragma unroll
  for (int c = 0; c < 4; c++) {
    int chunk = w * 4 + c, r = chunk * 8 + sr;
    gll16(A  + (size_t)(m0 + r) * K + scol, smem + chunk * 1024);
    gll16(Bt + (size_t)(n0 + r) * K + scol, smem + 16384 + chunk * 1024);
  }

  int cur = 0;
  for (int it = 0; it < 16; it++) {
    __syncthreads();
    char* Asc = smem + cur * 32768;
    char* Bsc = Asc + 16384;
    if (it < 15) {
      char* Asn = smem + (cur ^ 1) * 32768;
      const int kn = (it + 1) * 64;
#pragma unroll
      for (int c = 0; c < 4; c++) {
        int chunk = w * 4 + c, r = chunk * 8 + sr;
        gll16(A  + (size_t)(m0 + r) * K + kn + scol, Asn + chunk * 1024);
        gll16(Bt + (size_t)(n0 + r) * K + kn + scol, Asn + 16384 + chunk * 1024);
      }
    }
#pragma unroll
    for (int ks = 0; ks < 2; ks++) {
      f16x8 af[4], bf[4];
#pragma unroll
      for (int ii = 0; ii < 4; ii++) {
        af[ii] = *(const f16x8*)(Asc + lds_byte(wm + ii * 16 + li, ks * 4 + gq));
        bf[ii] = *(const f16x8*)(Bsc + lds_byte(wn + ii * 16 + li, ks * 4 + gq));
      }
#pragma unroll
      for (int mi = 0; mi < 4; mi++)
#pragma unroll
        for (int ni = 0; ni < 4; ni++)
          acc[mi][ni] = __builtin_amdgcn_mfma_f32_16x16x32_f16(af[mi], bf[ni], acc[mi][ni], 0, 0, 0);
    }
    cur ^= 1;
  }

  for (int mi = 0; mi < 4; mi++)
    for (int ni = 0; ni < 4; ni++) {
      const int r0  = m0 + wm + mi * 16 + gq * 4;
      const int col = n0 + wn + ni * 16 + li;
      const float bb = bias[col];
#pragma unroll
      for (int j = 0; j < 4; j++)
        C[(size_t)(r0 + j) * N + col] = acc[mi][ni][j] + bb;
    }
}

// ---------------- fused attention (split-k, 8 waves, 48KB LDS, V single-buffered) ----------------
// Per half (24KB): K dbuf @0/@8192, V @16384. Q frags direct from global.
// V(t) staged during QK^T(t)+softmax(t); drained by counted vmcnt(2) barrier (K(t+1) in flight).
__global__ __launch_bounds__(512, 4) void attn_fused(const f16* __restrict__ Qp,
                                                     const f16* __restrict__ Kp,
                                                     const f16* __restrict__ Vt,
                                                     const u32* __restrict__ mbits,
                                                     f16* __restrict__ outp) {
  // XCD-aware decode: all 16 q-tiles of one (b,h) land on one XCD for K/V L2 reuse
  const int flat = blockIdx.x;                 // 0..511
  const int xcd = flat & 7, jj = flat >> 3;    // jj 0..63
  const int qt = jj & 15;
  const int hb = xcd * 4 + (jj >> 4);          // 0..31
  const int h = hb & 15, b = hb >> 4;

  const int tid = threadIdx.x, l = tid & 63, w = tid >> 6;   // w 0..7
  const int lo = l & 31, hi = l >> 5;
  const int half = w >> 2, wsub = w & 3;
  const int q0 = qt * 128, wq = wsub * 32;

  __shared__ char smem[49152];                 // 2 halves x 24KB; reused as merge scratch
  char* hbase = smem + half * 24576;           // K0 @0, K1 @8192, V @16384

  const size_t qkbase = (size_t)b * Ss * Dd + (size_t)h * HDd;
  const f16* Vtb = Vt + (size_t)(b * Hh + h) * HDd * Ss;   // rows d (stride S), cols s
  const int sr = l >> 3, ss = l & 7;
  const int scol = ((ss ^ sr) << 3);           // pre-swizzled source col (f16 elems)

  // Q fragments straight from global (col q = wq+lo, d = 16c + 8*hi + e)
  const f16* Qrow = Qp + qkbase + (size_t)(q0 + wq + lo) * Dd;
  f16x8 qf[4];
#pragma unroll
  for (int c = 0; c < 4; c++) qf[c] = *(const f16x8*)(Qrow + 16 * c + 8 * hi);

  const int kt0 = half * 16;                   // first absolute tile of this half
  // prologue: issue K(0) into K[0]
  for (int c = 0; c < 2; c++) {
    int chunk = wsub * 2 + c, r = chunk * 8 + sr;
    gll16(Kp + qkbase + (size_t)(kt0 * 64 + r) * Dd + scol, hbase + chunk * 1024);
  }

  f32x16 accO0 = {0}, accO1 = {0};             // O^T[d][q]: q = lo, d-tiles 0-31 / 32-63
  float m_run = -1e30f, l_run = 0.f;           // per-lane; l covers this lane's k subset
  const u32* mrow = mbits + (size_t)(b * Ss + q0 + wq + lo) * 64;

  for (int it = 0; it < 16; it++) {
    const int kt = kt0 + it;
    // ---- barrier #1: K(it) drained block-wide; all waves done reading V(it-1) ----
    asm volatile("s_waitcnt vmcnt(0)" ::: "memory");
    __builtin_amdgcn_s_barrier();
    __builtin_amdgcn_sched_barrier(0);

    // stage V(it) (this-tile; covered by QK+softmax), then K(it+1) (full-tile span)
    for (int c = 0; c < 2; c++) {
      int chunk = wsub * 2 + c, r = chunk * 8 + sr;
      gll16(Vtb + (size_t)r * Ss + kt * 64 + scol, hbase + 16384 + chunk * 1024);
    }
    if (it < 15) {
      for (int c = 0; c < 2; c++) {
        int chunk = wsub * 2 + c, r = chunk * 8 + sr;
        gll16(Kp + qkbase + (size_t)((kt + 1) * 64 + r) * Dd + scol,
              hbase + ((it + 1) & 1) * 8192 + chunk * 1024);
      }
    }
    const char* Kb = hbase + (it & 1) * 8192;

    // QK^T (swapped): s0 = S^T rows k0..31, s1 = rows k32..63; col q = lo
    f32x16 s0 = {0}, s1 = {0};
    __builtin_amdgcn_s_setprio(1);
#pragma unroll
    for (int c = 0; c < 4; c++) {
      f16x8 kf0 = *(const f16x8*)(Kb + lds_byte(lo, 2 * c + hi));
      f16x8 kf1 = *(const f16x8*)(Kb + lds_byte(32 + lo, 2 * c + hi));
      s0 = __builtin_amdgcn_mfma_f32_32x32x16_f16(kf0, qf[c], s0, 0, 0, 0);
      s1 = __builtin_amdgcn_mfma_f32_32x32x16_f16(kf1, qf[c], s1, 0, 0, 0);
    }
    __builtin_amdgcn_s_setprio(0);

    // ---- online softmax, exp2 domain, defer-max ----
    uint2v mw = *(const uint2v*)(mrow + kt * 2);
    u32 wa = mw.x >> (hi << 2);                // this lane's k-bits start at 4*hi
    u32 wb = mw.y >> (hi << 2);

    float x0 = fmaxf(s0[0], s1[0]), x1 = fmaxf(s0[1], s1[1]);
    float x2 = fmaxf(s0[2], s1[2]), x3 = fmaxf(s0[3], s1[3]);
#pragma unroll
    for (int r = 4; r < 16; r += 4) {
      x0 = fmaxf(x0, fmaxf(s0[r],     s1[r]));
      x1 = fmaxf(x1, fmaxf(s0[r + 1], s1[r + 1]));
      x2 = fmaxf(x2, fmaxf(s0[r + 2], s1[r + 2]));
      x3 = fmaxf(x3, fmaxf(s0[r + 3], s1[r + 3]));
    }
    float pm = fmaxf(fmaxf(x0, x1), fmaxf(x2, x3));

    float mn;
    if (__all(pm <= m_run + 11.5f)) {
      mn = m_run;                              // deferred: p bounded by 2^11.5
    } else {
      pm = fmaxf(pm, __shfl_xor(pm, 32));      // per-q max across hi halves
      mn = fmaxf(m_run, pm);
      const float so = ex2(m_run - mn);
      m_run = mn;
      l_run *= so;
      accO0 *= so; accO1 *= so;
    }

    float racc = 0.f;
#pragma unroll
    for (int r = 0; r < 16; r++) {
      const int kk = (r & 3) + 8 * (r >> 2);   // + 4*hi already shifted out of wa/wb
      u32 ma = (u32)(((int)(wa << (31 - kk))) >> 31);
      u32 mb = (u32)(((int)(wb << (31 - kk))) >> 31);
      float e0 = __uint_as_float(__float_as_uint(ex2(s0[r] - mn)) & ma);
      float e1 = __uint_as_float(__float_as_uint(ex2(s1[r] - mn)) & mb);
      s0[r] = e0; s1[r] = e1;
      racc += e0 + e1;
    }
    l_run += racc;                             // per-lane partial; cross-lane at end

    // ---- P -> f16 A/B-frags via cvt_pkrtz + permlane32_swap (no LDS) ----
    u32 pw[16];
#pragma unroll
    for (int j = 0; j < 8; j++) {
      H2U a, c;
      a.h = __builtin_amdgcn_cvt_pkrtz(s0[2 * j], s0[2 * j + 1]);
      c.h = __builtin_amdgcn_cvt_pkrtz(s1[2 * j], s1[2 * j + 1]);
      pw[j] = a.u; pw[8 + j] = c.u;
    }
#pragma unroll
    for (int c = 0; c < 4; c++) {
      asm volatile("v_permlane32_swap_b32 %0, %1" : "+v"(pw[4 * c]), "+v"(pw[4 * c + 2]));
      asm volatile("v_permlane32_swap_b32 %0, %1" : "+v"(pw[4 * c + 1]), "+v"(pw[4 * c + 3]));
    }

    // ---- barrier #2: V(it) drained (counted; K(it+1) stays in flight) ----
    if (it < 15) asm volatile("s_waitcnt vmcnt(2)" ::: "memory");
    else         asm volatile("s_waitcnt vmcnt(0)" ::: "memory");
    __builtin_amdgcn_s_barrier();
    __builtin_amdgcn_sched_barrier(0);
    const char* Vb = hbase + 16384;

    // ---- PV: O^T[d][q] += Vt[d][k] * P[q][k] ----
    __builtin_amdgcn_s_setprio(1);
#pragma unroll
    for (int c = 0; c < 4; c++) {
      union { u32 u[4]; f16x8 v; } pu;
      pu.u[0] = pw[4 * c]; pu.u[1] = pw[4 * c + 1];
      pu.u[2] = pw[4 * c + 2]; pu.u[3] = pw[4 * c + 3];
      f16x8 vf0 = *(const f16x8*)(Vb + lds_byte(lo, 2 * c + hi));
      f16x8 vf1 = *(const f16x8*)(Vb + lds_byte(32 + lo, 2 * c + hi));
      accO0 = __builtin_amdgcn_mfma_f32_32x32x16_f16(vf0, pu.v, accO0, 0, 0, 0);
      accO1 = __builtin_amdgcn_mfma_f32_32x32x16_f16(vf1, pu.v, accO1, 0, 0, 0);
    }
    __builtin_amdgcn_s_setprio(0);
  }

  // ---- merge halves (m-aware, per-lane); stride 35 floats (odd -> conflict-free) ----
  __syncthreads();
  float* mg = (float*)smem;                    // 256 lanes x 35 floats = 35840 B
  if (half == 1) {
    float* p = mg + (size_t)(wsub * 64 + l) * 35;
#pragma unroll
    for (int r = 0; r < 16; r++) { p[r] = accO0[r]; p[16 + r] = accO1[r]; }
    p[32] = m_run; p[33] = l_run;
  }
  __syncthreads();
  if (half == 1) return;

  const float* p = mg + (size_t)(wsub * 64 + l) * 35;
  const float mB = p[32], lB = p[33];
  const float m = fmaxf(m_run, mB);
  const float fA = ex2(m_run - m), fB = ex2(mB - m);
  float lmerged = l_run * fA + lB * fB;
#pragma unroll
  for (int r = 0; r < 16; r++) {
    accO0[r] = accO0[r] * fA + p[r] * fB;
    accO1[r] = accO1[r] * fA + p[16 + r] * fB;
  }
  const float lf = lmerged + __shfl_xor(lmerged, 32);   // combine hi=0/1 k-subsets
  const float inv = 1.0f / lf;
  asm volatile("" ::: "memory");               // p reads complete before Ot writes (alias fence)

  // ---- epilogue: O^T -> O via this wave's own consumed merge slice (in-order LDS) ----
  char* Ot = smem + wsub * 8960;               // 4KB used of the 8960B slice
#pragma unroll
  for (int j = 0; j < 8; j++) {
    H2U pk;
    pk.h = __builtin_amdgcn_cvt_pkrtz(accO0[2 * j] * inv, accO0[2 * j + 1] * inv);
    int slot = (j >> 1);
    int addr = lo * 128 + (((slot ^ (lo & 7)) & 7) << 4) + 4 * (j & 1) + 8 * hi;
    *(u32*)(Ot + addr) = pk.u;
  }
#pragma unroll
  for (int j = 0; j < 8; j++) {
    H2U pk;
    pk.h = __builtin_amdgcn_cvt_pkrtz(accO1[2 * j] * inv, accO1[2 * j + 1] * inv);
    int slot = (j >> 1) + 4;
    int addr = lo * 128 + (((slot ^ (lo & 7)) & 7) << 4) + 4 * (j & 1) + 8 * hi;
    *(u32*)(Ot + addr) = pk.u;
  }
  asm volatile("s_waitcnt lgkmcnt(0)" ::: "memory");   // same-wave cross-lane LDS visibility
  {
    const int q = l >> 1, halfq = l & 1;
    f16* gbase = outp + qkbase + (size_t)(q0 + wq + q) * Dd + halfq * 32;
#pragma unroll
    for (int c = 0; c < 4; c++) {
      int byte = q * 128 + ((((halfq * 4 + c) ^ (q & 7)) & 7) << 4);
      f16x8 v = *(const f16x8*)(Ot + byte);
      *(f16x8*)(gbase + c * 8) = v;
    }
  }
}

// ---------------- launch ----------------
extern "C" void kernel_launch(void* const* d_in, const int* in_sizes, int n_in,
                              void* d_out, int out_size, void* d_ws, size_t ws_size,
                              hipStream_t stream) {
  const float* query = (const float*)d_in[0];
  const float* key_  = (const float*)d_in[1];
  const float* value = (const float*)d_in[2];
  const int*   mask  = (const int*)d_in[3];
  const float* Wq = (const float*)d_in[4];
  const float* bq = (const float*)d_in[5];
  const float* Wk = (const float*)d_in[6];
  const float* bk = (const float*)d_in[7];
  const float* Wv = (const float*)d_in[8];
  const float* bv = (const float*)d_in[9];
  const float* Wo = (const float*)d_in[10];
  const float* bo = (const float*)d_in[11];

  char* ws = (char*)d_ws;
  f16* Wt  = (f16*)(ws + OFF_WT);
  f16* QKV = (f16*)(ws + OFF_QKV);
  f16* ATT = (f16*)(ws + OFF_ATT);
  unsigned* MB = (unsigned*)(ws + OFF_MB);

  prep<<<dim3(32768 + 4096), 256, 0, stream>>>(mask, MB, Wq, Wk, Wv, Wo, Wt);
  gemm_qkv<<<dim3(768), 256, 0, stream>>>(query, key_, value, Wt, bq, bk, bv, QKV);
  attn_fused<<<dim3(512), 512, 0, stream>>>(QKV, QKV + (size_t)M_ROWS * Dd,
                                            QKV + 2 * (size_t)M_ROWS * Dd, MB, ATT);
  gemm_out<<<dim3(256), 256, 0, stream>>>(ATT, Wt + 3 * (size_t)Dd * Dd, bo, (float*)d_out);
}

// Round 19
// 132.779 us; speedup vs baseline: 1.1095x; 1.0169x over previous
//
#include <hip/hip_runtime.h>
#include <stdint.h>

typedef _Float16 f16;
typedef _Float16 f16x4 __attribute__((ext_vector_type(4)));
typedef _Float16 f16x8 __attribute__((ext_vector_type(8)));
typedef __fp16 hf16x2 __attribute__((ext_vector_type(2)));   // cvt_pkrtz return type
typedef float f32x4 __attribute__((ext_vector_type(4)));
typedef float f32x16 __attribute__((ext_vector_type(16)));
typedef unsigned u32;
typedef unsigned uint2v __attribute__((ext_vector_type(2)));

static constexpr int Bb = 2, Ss = 2048, Dd = 1024, Hh = 16, HDd = 64;
static constexpr int M_ROWS = Bb * Ss; // 4096

// ---- workspace layout (bytes) ----
static constexpr size_t OFF_WT  = 24ull << 20;             // WtQ..WtO f16: 4 * 2 MiB
static constexpr size_t OFF_QKV = 32ull << 20;             // Q,K row-major; V transposed [b][h][d][s]
static constexpr size_t OFF_ATT = 56ull << 20;             // attn f16: 8 MiB
static constexpr size_t OFF_MB  = 64ull << 20;             // mask bits: 1 MiB

__device__ __forceinline__ void gll16(const void* g, void* l) {
  __builtin_amdgcn_global_load_lds((__attribute__((address_space(1))) const void*)g,
                                   (__attribute__((address_space(3))) void*)l, 16, 0, 0);
}

// [rows][64 f16] tile (row = 128 B): byte addr of 16B slot `slot`, XOR-swizzled.
__device__ __forceinline__ int lds_byte(int row, int slot) {
  return row * 128 + (((slot ^ (row & 7)) & 7) << 4);
}

// raw v_exp_f32 (input already in log2 domain)
__device__ __forceinline__ float ex2(float x) {
  float r; asm("v_exp_f32 %0, %1" : "=v"(r) : "v"(x)); return r;
}

union H2U { hf16x2 h; u32 u; };

// ---------------- prep: pack mask bits + transpose/convert weights ----------------
__global__ __launch_bounds__(256) void prep(const int* __restrict__ mask,
                                            unsigned* __restrict__ bits,
                                            const float* __restrict__ wq,
                                            const float* __restrict__ wk,
                                            const float* __restrict__ wv,
                                            const float* __restrict__ wo,
                                            f16* __restrict__ wt) {
  const int bid = blockIdx.x;
  __shared__ float t[32][33];
  if (bid < 32768) {
    size_t i = (size_t)bid * 256 + threadIdx.x;    // one thread per mask int
    int v = mask[i];
    unsigned long long bm = __ballot(v != 0);
    if ((threadIdx.x & 63) == 0) {
      size_t w = i >> 5;
      bits[w]     = (unsigned)bm;
      bits[w + 1] = (unsigned)(bm >> 32);
    }
  } else {
    const int wb = bid - 32768;                    // z*1024 + by*32 + bx
    const int z = wb >> 10, by = (wb >> 5) & 31, bx = wb & 31;
    const float* W = z == 0 ? wq : z == 1 ? wk : z == 2 ? wv : wo;
    f16* Wt = wt + (size_t)z * Dd * Dd;
    const int tx = threadIdx.x & 31, ty = threadIdx.x >> 5;   // (32, 8)
    const int k0 = by * 32, n0 = bx * 32;
    for (int i = 0; i < 32; i += 8) t[ty + i][tx] = W[(size_t)(k0 + ty + i) * Dd + n0 + tx];
    __syncthreads();
    for (int i = 0; i < 32; i += 8) Wt[(size_t)(n0 + ty + i) * Dd + k0 + tx] = (f16)t[tx][ty + i];
  }
}

// ---------------- QKV GEMM: 2-iteration-deep pipeline (counted vmcnt, tri-buffer B) ----------------
// Schedule/iter t: vmcnt(12) [drain loads(t), keep loads(t+1)] -> ds_write A(t) ->
// lgkmcnt(0)+s_barrier -> issue loads(t+2) -> MFMA(t).  LDS: bufA[2]x16K | bufB[3]x16K = 80 KB.
// z==0: output scaled by 0.125*log2e; z==2: output stored TRANSPOSED as Vt[b][h][d][s]
__global__ __launch_bounds__(256) void gemm_qkv(const float* __restrict__ qin,
                                                const float* __restrict__ kin,
                                                const float* __restrict__ vin,
                                                const f16* __restrict__ Btbase,
                                                const float* __restrict__ b0,
                                                const float* __restrict__ b1,
                                                const float* __restrict__ b2,
                                                f16* __restrict__ Cbase) {
  constexpr int K = Dd, N = Dd;
  const int f = blockIdx.x;                 // 0..767
  const int z = f >> 8, i = f & 255;
  const int xg = i & 7, sl = i >> 3;        // XCD-chunked m-panel map (R10)
  const int m0 = (xg * 4 + (sl >> 3)) * 128, n0 = (sl & 7) * 128;
  const float* A = z == 0 ? qin : z == 1 ? kin : vin;
  const f16* Bt = Btbase + (size_t)z * N * K;
  const float* bias = z == 0 ? b0 : z == 1 ? b1 : b2;

  __shared__ char smem[81920];              // bufA[2] @ 0,16384 ; bufB[3] @ 32768+
  const int tid = threadIdx.x, l = tid & 63, w = tid >> 6;   // w 0..3
  const int li = l & 15, gq = l >> 4;
  const int wm = (w >> 1) * 64, wn = (w & 1) * 64;
  const int sr = l >> 3, ss = l & 7;
  const int scol = ((ss ^ sr) << 3);        // pre-swizzled source col (elems)

  f32x4 acc[4][4];
  for (int mi = 0; mi < 4; mi++)
    for (int ni = 0; ni < 4; ni++) acc[mi][ni] = f32x4{0.f, 0.f, 0.f, 0.f};

  float4 a0[2][4], a1[2][4];                // two in-flight A-register sets (parity t&1)

  // ---- prologue: issue loads(0) and loads(1) (12 vm-ops each) ----
#pragma unroll
  for (int t = 0; t < 2; t++) {
    const int kt = t * 64;
#pragma unroll
    for (int c = 0; c < 4; c++) {
      int chunk = w * 4 + c, r = chunk * 8 + sr;
      gll16(Bt + (size_t)(n0 + r) * K + kt + scol, smem + 32768 + t * 16384 + chunk * 1024);
      const float* src = A + (size_t)(m0 + r) * K + kt + scol;
      a0[t][c] = *(const float4*)src;
      a1[t][c] = *(const float4*)(src + 4);
    }
  }

#pragma unroll
  for (int t = 0; t < 16; t++) {
    // [A] drain loads(t); keep loads(t+1) (12 ops) in flight
    if (t < 15) asm volatile("s_waitcnt vmcnt(12)" ::: "memory");
    else        asm volatile("s_waitcnt vmcnt(0)"  ::: "memory");

    // [B] cvt + linear ds_write A(t) into bufA[t&1] (read at [D] this iter, post-barrier)
    {
      char* bufA = smem + (t & 1) * 16384;
#pragma unroll
      for (int c = 0; c < 4; c++) {
        int chunk = w * 4 + c;
        H2U h0, h1, h2, h3;
        h0.h = __builtin_amdgcn_cvt_pkrtz(a0[t & 1][c].x, a0[t & 1][c].y);
        h1.h = __builtin_amdgcn_cvt_pkrtz(a0[t & 1][c].z, a0[t & 1][c].w);
        h2.h = __builtin_amdgcn_cvt_pkrtz(a1[t & 1][c].x, a1[t & 1][c].y);
        h3.h = __builtin_amdgcn_cvt_pkrtz(a1[t & 1][c].z, a1[t & 1][c].w);
        union { u32 uu[4]; f16x8 v8; } pk;
        pk.uu[0] = h0.u; pk.uu[1] = h1.u; pk.uu[2] = h2.u; pk.uu[3] = h3.u;
        *(f16x8*)(bufA + chunk * 1024 + l * 16) = pk.v8;
      }
    }
    asm volatile("s_waitcnt lgkmcnt(0)" ::: "memory");
    __builtin_amdgcn_s_barrier();           // all staging of tile t visible; all reads of
                                            // bufB[(t+2)%3] (== (t-1)%3, iter t-1) finished

    // [C] issue loads(t+2): B -> bufB[(t+2)%3], A -> regs set (t&1) just freed at [B]
    if (t + 2 < 16) {
      const int tn = t + 2, kn = tn * 64;
#pragma unroll
      for (int c = 0; c < 4; c++) {
        int chunk = w * 4 + c, r = chunk * 8 + sr;
        gll16(Bt + (size_t)(n0 + r) * K + kn + scol,
              smem + 32768 + (tn % 3) * 16384 + chunk * 1024);
        const float* src = A + (size_t)(m0 + r) * K + kn + scol;
        a0[tn & 1][c] = *(const float4*)src;
        a1[tn & 1][c] = *(const float4*)(src + 4);
      }
    }
    __builtin_amdgcn_sched_barrier(0);      // pin issue before MFMA block

    // [D] MFMA(t)
    const char* Asc = smem + (t & 1) * 16384;
    const char* Bsc = smem + 32768 + (t % 3) * 16384;
#pragma unroll
    for (int ks = 0; ks < 2; ks++) {
      f16x8 af[4], bf[4];
#pragma unroll
      for (int ii = 0; ii < 4; ii++) {
        af[ii] = *(const f16x8*)(Asc + lds_byte(wm + ii * 16 + li, ks * 4 + gq));
        bf[ii] = *(const f16x8*)(Bsc + lds_byte(wn + ii * 16 + li, ks * 4 + gq));
      }
#pragma unroll
      for (int mi = 0; mi < 4; mi++)
#pragma unroll
        for (int ni = 0; ni < 4; ni++)
          acc[mi][ni] = __builtin_amdgcn_mfma_f32_16x16x32_f16(af[mi], bf[ni], acc[mi][ni], 0, 0, 0);
    }
  }

  const float scl = (z == 0) ? 0.18033688011112042f : 1.0f;   // 0.125*log2e
  if (z == 2) {
    // transposed V: Vt[(b*16+h)*64 + d][s], packed f16x4 along s
    f16* Vt = Cbase + (size_t)2 * M_ROWS * N;
#pragma unroll
    for (int mi = 0; mi < 4; mi++)
#pragma unroll
      for (int ni = 0; ni < 4; ni++) {
        const int col = n0 + wn + ni * 16 + li;        // h*64 + d
        const int r0  = m0 + wm + mi * 16 + gq * 4;    // global s index (4-aligned)
        const int bb_ = r0 >> 11, s = r0 & 2047;
        const float bv = bias[col];
        f16x4 pk;
#pragma unroll
        for (int j = 0; j < 4; j++) pk[j] = (f16)(acc[mi][ni][j] + bv);
        *(f16x4*)(Vt + ((size_t)(bb_ * Hh) << 17) + (size_t)col * Ss + s) = pk;
      }
  } else {
    for (int mi = 0; mi < 4; mi++)
      for (int ni = 0; ni < 4; ni++) {
        const int r0  = m0 + wm + mi * 16 + gq * 4;
        const int col = n0 + wn + ni * 16 + li;
        const float bb = bias[col];
#pragma unroll
        for (int j = 0; j < 4; j++) {
          float val = (acc[mi][ni][j] + bb) * scl;
          Cbase[(size_t)z * M_ROWS * N + (size_t)(r0 + j) * N + col] = (f16)val;
        }
      }
  }
}

// ---------------- output GEMM: 2-phase double-buffered, f16 A (attn), fp32 out ----------------
__global__ __launch_bounds__(256) void gemm_out(const f16* __restrict__ A,
                                                const f16* __restrict__ Bt,
                                                const float* __restrict__ bias,
                                                float* __restrict__ C) {
  constexpr int K = Dd, N = Dd;
  const int f = blockIdx.x;                 // 0..255
  const int xg = f & 7, sl = f >> 3;
  const int m0 = (xg * 4 + (sl >> 3)) * 128, n0 = (sl & 7) * 128;
  __shared__ char smem[65536];              // buf[2] x (As 16K | Bs 16K)
  const int tid = threadIdx.x, l = tid & 63, w = tid >> 6;
  const int li = l & 15, gq = l >> 4;
  const int wm = (w >> 1) * 64, wn = (w & 1) * 64;
  const int sr = l >> 3, ss = l & 7;
  const int scol = ((ss ^ sr) << 3);

  f32x4 acc[4][4];
  for (int mi = 0; mi < 4; mi++)
    for (int ni = 0; ni < 4; ni++) acc[mi][ni] = f32x4{0.f, 0.f, 0.f, 0.f};

  // prologue: stage tile 0 into buf0
#pragma unroll
  for (int c = 0; c < 4; c++) {
    int chunk = w * 4 + c, r = chunk * 8 + sr;
    gll16(A  + (size_t)(m0 + r) * K + scol, smem + chunk * 1024);
    gll16(Bt + (size_t)(n0 + r) * K + scol, smem + 16384 + chunk * 1024);
  }

  int cur = 0;
  for (int it = 0; it < 16; it++) {
    __syncthreads();
    char* Asc = smem + cur * 32768;
    char* Bsc = Asc + 16384;
    if (it < 15) {
      char* Asn = smem + (cur ^ 1) * 32768;
      const int kn = (it + 1) * 64;
#pragma unroll
      for (int c = 0; c < 4; c++) {
        int chunk = w * 4 + c, r = chunk * 8 + sr;
        gll16(A  + (size_t)(m0 + r) * K + kn + scol, Asn + chunk * 1024);
        gll16(Bt + (size_t)(n0 + r) * K + kn + scol, Asn + 16384 + chunk * 1024);
      }
    }
#pragma unroll
    for (int ks = 0; ks < 2; ks++) {
      f16x8 af[4], bf[4];
#pragma unroll
      for (int ii = 0; ii < 4; ii++) {
        af[ii] = *(const f16x8*)(Asc + lds_byte(wm + ii * 16 + li, ks * 4 + gq));
        bf[ii] = *(const f16x8*)(Bsc + lds_byte(wn + ii * 16 + li, ks * 4 + gq));
      }
#pragma unroll
      for (int mi = 0; mi < 4; mi++)
#pragma unroll
        for (int ni = 0; ni < 4; ni++)
          acc[mi][ni] = __builtin_amdgcn_mfma_f32_16x16x32_f16(af[mi], bf[ni], acc[mi][ni], 0, 0, 0);
    }
    cur ^= 1;
  }

  for (int mi = 0; mi < 4; mi++)
    for (int ni = 0; ni < 4; ni++) {
      const int r0  = m0 + wm + mi * 16 + gq * 4;
      const int col = n0 + wn + ni * 16 + li;
      const float bb = bias[col];
#pragma unroll
      for (int j = 0; j < 4; j++)
        C[(size_t)(r0 + j) * N + col] = acc[mi][ni][j] + bb;
    }
}

// ---------------- fused attention (split-k, 8 waves, defer-max exp2 softmax) — R15 proven ----------------
__global__ __launch_bounds__(512, 4) void attn_fused(const f16* __restrict__ Qp,
                                                     const f16* __restrict__ Kp,
                                                     const f16* __restrict__ Vt,
                                                     const u32* __restrict__ mbits,
                                                     f16* __restrict__ outp) {
  // XCD-aware decode: all 16 q-tiles of one (b,h) land on one XCD for K/V L2 reuse
  const int flat = blockIdx.x;                 // 0..511
  const int xcd = flat & 7, jj = flat >> 3;    // jj 0..63
  const int qt = jj & 15;
  const int hb = xcd * 4 + (jj >> 4);          // 0..31
  const int h = hb & 15, b = hb >> 4;

  const int tid = threadIdx.x, l = tid & 63, w = tid >> 6;   // w 0..7
  const int lo = l & 31, hi = l >> 5;
  const int half = w >> 2, wsub = w & 3;
  const int q0 = qt * 128, wq = wsub * 32;

  __shared__ char smem[65536];
  // per half: hbase = half*32768; buf0 = +0 (K 8K | V 8K), buf1 = +16384.
  // Q (16K) staged in half0's buf1 [16384:32768), freed after qf regs loaded.
  char* hbase = smem + half * 32768;
  char* Qst = smem + 16384;

  const size_t qkbase = (size_t)b * Ss * Dd + (size_t)h * HDd;
  const f16* Vtb = Vt + (size_t)(b * Hh + h) * HDd * Ss;   // rows d (stride S), cols s
  const int sr = l >> 3, ss = l & 7;
  const int scol = ((ss ^ sr) << 3);           // pre-swizzled source col (f16 elems)

  // stage Q (16 chunks over 8 waves) + this half's tile 0 into buf0
  for (int c = 0; c < 2; c++) {
    int chunk = w * 2 + c, r = chunk * 8 + sr;
    gll16(Qp + qkbase + (size_t)(q0 + r) * Dd + scol, Qst + chunk * 1024);
  }
  const int kt0 = half * 16;                   // first absolute tile of this half
  for (int c = 0; c < 2; c++) {
    int chunk = wsub * 2 + c, r = chunk * 8 + sr;
    gll16(Kp + qkbase + (size_t)(kt0 * 64 + r) * Dd + scol, hbase + chunk * 1024);
    gll16(Vtb + (size_t)r * Ss + kt0 * 64 + scol, hbase + 8192 + chunk * 1024);
  }
  __syncthreads();

  f16x8 qf[4];   // B-frag: col q = wq+lo, k(=d) = 16c + 8*hi + e
#pragma unroll
  for (int c = 0; c < 4; c++)
    qf[c] = *(const f16x8*)(Qst + lds_byte(wq + lo, 2 * c + hi));
  __syncthreads();   // all waves' Q reads done before buf1 prefetch overwrites it

  f32x16 accO0 = {0}, accO1 = {0};             // O^T[d][q]: q = lo, d-tiles 0-31 / 32-63
  float m_run = -1e30f, l_run = 0.f;           // per-lane; l covers this lane's k subset
  const u32* mrow = mbits + (size_t)(b * Ss + q0 + wq + lo) * 64;

  for (int it = 0; it < 16; it++) {
    const int kt = kt0 + it;
    if (it) __syncthreads();                   // cur-buf loads drained; other buf free
    char* bufc = hbase + (it & 1) * 16384;
    if (it < 15) {
      char* bufn = hbase + ((it + 1) & 1) * 16384;
      const int k0n = (kt + 1) * 64;
      for (int c = 0; c < 2; c++) {
        int chunk = wsub * 2 + c, r = chunk * 8 + sr;
        gll16(Kp + qkbase + (size_t)(k0n + r) * Dd + scol, bufn + chunk * 1024);
        gll16(Vtb + (size_t)r * Ss + k0n + scol, bufn + 8192 + chunk * 1024);
      }
    }
    const char* Kb = bufc;
    const char* Vb = bufc + 8192;

    // QK^T (swapped): s0 = S^T rows k0..31, s1 = rows k32..63; col q = lo
    f32x16 s0 = {0}, s1 = {0};
    __builtin_amdgcn_s_setprio(1);
#pragma unroll
    for (int c = 0; c < 4; c++) {
      f16x8 kf0 = *(const f16x8*)(Kb + lds_byte(lo, 2 * c + hi));
      f16x8 kf1 = *(const f16x8*)(Kb + lds_byte(32 + lo, 2 * c + hi));
      s0 = __builtin_amdgcn_mfma_f32_32x32x16_f16(kf0, qf[c], s0, 0, 0, 0);
      s1 = __builtin_amdgcn_mfma_f32_32x32x16_f16(kf1, qf[c], s1, 0, 0, 0);
    }
    __builtin_amdgcn_s_setprio(0);

    // ---- online softmax, exp2 domain, defer-max ----
    uint2v mw = *(const uint2v*)(mrow + kt * 2);
    u32 wa = mw.x >> (hi << 2);                // this lane's k-bits start at 4*hi
    u32 wb = mw.y >> (hi << 2);

    float x0 = fmaxf(s0[0], s1[0]), x1 = fmaxf(s0[1], s1[1]);
    float x2 = fmaxf(s0[2], s1[2]), x3 = fmaxf(s0[3], s1[3]);
#pragma unroll
    for (int r = 4; r < 16; r += 4) {
      x0 = fmaxf(x0, fmaxf(s0[r],     s1[r]));
      x1 = fmaxf(x1, fmaxf(s0[r + 1], s1[r + 1]));
      x2 = fmaxf(x2, fmaxf(s0[r + 2], s1[r + 2]));
      x3 = fmaxf(x3, fmaxf(s0[r + 3], s1[r + 3]));
    }
    float pm = fmaxf(fmaxf(x0, x1), fmaxf(x2, x3));

    float mn;
    if (__all(pm <= m_run + 11.5f)) {
      mn = m_run;                              // deferred: p bounded by 2^11.5
    } else {
      pm = fmaxf(pm, __shfl_xor(pm, 32));      // per-q max across hi halves
      mn = fmaxf(m_run, pm);
      const float so = ex2(m_run - mn);
      m_run = mn;
      l_run *= so;
      accO0 *= so; accO1 *= so;
    }

    float racc = 0.f;
#pragma unroll
    for (int r = 0; r < 16; r++) {
      const int kk = (r & 3) + 8 * (r >> 2);   // + 4*hi already shifted out of wa/wb
      u32 ma = (u32)(((int)(wa << (31 - kk))) >> 31);
      u32 mb = (u32)(((int)(wb << (31 - kk))) >> 31);
      float e0 = __uint_as_float(__float_as_uint(ex2(s0[r] - mn)) & ma);
      float e1 = __uint_as_float(__float_as_uint(ex2(s1[r] - mn)) & mb);
      s0[r] = e0; s1[r] = e1;
      racc += e0 + e1;
    }
    l_run += racc;                             // per-lane partial; cross-lane at end

    // ---- P -> f16 A/B-frags via cvt_pkrtz + permlane32_swap (no LDS) ----
    u32 pw[16];
#pragma unroll
    for (int j = 0; j < 8; j++) {
      H2U a, c;
      a.h = __builtin_amdgcn_cvt_pkrtz(s0[2 * j], s0[2 * j + 1]);
      c.h = __builtin_amdgcn_cvt_pkrtz(s1[2 * j], s1[2 * j + 1]);
      pw[j] = a.u; pw[8 + j] = c.u;
    }
#pragma unroll
    for (int c = 0; c < 4; c++) {
      asm volatile("v_permlane32_swap_b32 %0, %1" : "+v"(pw[4 * c]), "+v"(pw[4 * c + 2]));
      asm volatile("v_permlane32_swap_b32 %0, %1" : "+v"(pw[4 * c + 1]), "+v"(pw[4 * c + 3]));
    }

    // ---- PV: O^T[d][q] += Vt[d][k] * P[q][k] ----
    __builtin_amdgcn_s_setprio(1);
#pragma unroll
    for (int c = 0; c < 4; c++) {
      union { u32 u[4]; f16x8 v; } pu;
      pu.u[0] = pw[4 * c]; pu.u[1] = pw[4 * c + 1];
      pu.u[2] = pw[4 * c + 2]; pu.u[3] = pw[4 * c + 3];
      f16x8 vf0 = *(const f16x8*)(Vb + lds_byte(lo, 2 * c + hi));
      f16x8 vf1 = *(const f16x8*)(Vb + lds_byte(32 + lo, 2 * c + hi));
      accO0 = __builtin_amdgcn_mfma_f32_32x32x16_f16(vf0, pu.v, accO0, 0, 0, 0);
      accO1 = __builtin_amdgcn_mfma_f32_32x32x16_f16(vf1, pu.v, accO1, 0, 0, 0);
    }
    __builtin_amdgcn_s_setprio(0);
  }

  // ---- merge halves (m-aware, per-lane); stride 35 floats (odd -> conflict-free) ----
  __syncthreads();
  float* mg = (float*)smem;                    // 256 lanes x 35 floats = 35840 B
  if (half == 1) {
    float* p = mg + (size_t)(wsub * 64 + l) * 35;
#pragma unroll
    for (int r = 0; r < 16; r++) { p[r] = accO0[r]; p[16 + r] = accO1[r]; }
    p[32] = m_run; p[33] = l_run;
  }
  __syncthreads();
  if (half == 1) return;

  const float* p = mg + (size_t)(wsub * 64 + l) * 35;
  const float mB = p[32], lB = p[33];
  const float m = fmaxf(m_run, mB);
  const float fA = ex2(m_run - m), fB = ex2(mB - m);
  float lmerged = l_run * fA + lB * fB;
#pragma unroll
  for (int r = 0; r < 16; r++) {
    accO0[r] = accO0[r] * fA + p[r] * fB;
    accO1[r] = accO1[r] * fA + p[16 + r] * fB;
  }
  const float lf = lmerged + __shfl_xor(lmerged, 32);   // combine hi=0/1 k-subsets
  const float inv = 1.0f / lf;

  // ---- epilogue: transpose O^T -> O through per-wave LDS, store ----
  char* Ot = smem + 40960 + wsub * 4096;       // per-wave 32q x 64d f16 (swizzled)
#pragma unroll
  for (int j = 0; j < 8; j++) {
    H2U pk;
    pk.h = __builtin_amdgcn_cvt_pkrtz(accO0[2 * j] * inv, accO0[2 * j + 1] * inv);
    int slot = (j >> 1);
    int addr = lo * 128 + (((slot ^ (lo & 7)) & 7) << 4) + 4 * (j & 1) + 8 * hi;
    *(u32*)(Ot + addr) = pk.u;
  }
#pragma unroll
  for (int j = 0; j < 8; j++) {
    H2U pk;
    pk.h = __builtin_amdgcn_cvt_pkrtz(accO1[2 * j] * inv, accO1[2 * j + 1] * inv);
    int slot = (j >> 1) + 4;
    int addr = lo * 128 + (((slot ^ (lo & 7)) & 7) << 4) + 4 * (j & 1) + 8 * hi;
    *(u32*)(Ot + addr) = pk.u;
  }
  asm volatile("s_waitcnt lgkmcnt(0)" ::: "memory");   // same-wave cross-lane LDS visibility
  {
    const int q = l >> 1, halfq = l & 1;
    f16* gbase = outp + qkbase + (size_t)(q0 + wq + q) * Dd + halfq * 32;
#pragma unroll
    for (int c = 0; c < 4; c++) {
      int byte = q * 128 + ((((halfq * 4 + c) ^ (q & 7)) & 7) << 4);
      f16x8 v = *(const f16x8*)(Ot + byte);
      *(f16x8*)(gbase + c * 8) = v;
    }
  }
}

// ---------------- launch ----------------
extern "C" void kernel_launch(void* const* d_in, const int* in_sizes, int n_in,
                              void* d_out, int out_size, void* d_ws, size_t ws_size,
                              hipStream_t stream) {
  const float* query = (const float*)d_in[0];
  const float* key_  = (const float*)d_in[1];
  const float* value = (const float*)d_in[2];
  const int*   mask  = (const int*)d_in[3];
  const float* Wq = (const float*)d_in[4];
  const float* bq = (const float*)d_in[5];
  const float* Wk = (const float*)d_in[6];
  const float* bk = (const float*)d_in[7];
  const float* Wv = (const float*)d_in[8];
  const float* bv = (const float*)d_in[9];
  const float* Wo = (const float*)d_in[10];
  const float* bo = (const float*)d_in[11];

  char* ws = (char*)d_ws;
  f16* Wt  = (f16*)(ws + OFF_WT);
  f16* QKV = (f16*)(ws + OFF_QKV);
  f16* ATT = (f16*)(ws + OFF_ATT);
  unsigned* MB = (unsigned*)(ws + OFF_MB);

  prep<<<dim3(32768 + 4096), 256, 0, stream>>>(mask, MB, Wq, Wk, Wv, Wo, Wt);
  gemm_qkv<<<dim3(768), 256, 0, stream>>>(query, key_, value, Wt, bq, bk, bv, QKV);
  attn_fused<<<dim3(512), 512, 0, stream>>>(QKV, QKV + (size_t)M_ROWS * Dd,
                                            QKV + 2 * (size_t)M_ROWS * Dd, MB, ATT);
  gemm_out<<<dim3(256), 256, 0, stream>>>(ATT, Wt + 3 * (size_t)Dd * Dd, bo, (float*)d_out);
}